// Round 1
// baseline (829.801 us; speedup 1.0000x reference)
//
#include <hip/hip_runtime.h>

#define D 128

// ---------------- degree kernels ----------------
__global__ void k_init_deg(float* __restrict__ deg, int n) {
    int i = blockIdx.x * blockDim.x + threadIdx.x;
    if (i < n) deg[i] = 1.0f;  // self-loop contributes 1
}

__global__ void k_deg_edges(const int* __restrict__ dst, float* __restrict__ deg, int nE) {
    int e = blockIdx.x * blockDim.x + threadIdx.x;
    if (e < nE) atomicAdd(&deg[dst[e]], 1.0f);
}

__global__ void k_fin_deg(float* __restrict__ deg, int n) {
    int i = blockIdx.x * blockDim.x + threadIdx.x;
    if (i < n) deg[i] = rsqrtf(deg[i]);  // deg >= 1 always
}

// ---------------- GEMM: out[n,128] = (relu?)(X) @ W ----------------
// 256 threads: 8 rows in flight, 32 threads/row, each thread 4 consecutive cols (float4).
// W (64KB) staged once per block in LDS; 8 row-groups per block to amortize.
#define ROWS_PER_ITER 8
#define GROUPS 8
#define ROWS_PER_BLOCK (ROWS_PER_ITER * GROUPS)

template <bool RELU>
__global__ __launch_bounds__(256) void k_gemm(const float* __restrict__ X,
                                              const float* __restrict__ W,
                                              float* __restrict__ out, int n) {
    __shared__ float Wl[D * D];          // 64 KB
    __shared__ float xr[ROWS_PER_ITER * D];  // 4 KB
    const int tid = threadIdx.x;

    for (int i = tid; i < D * D; i += 256) Wl[i] = W[i];
    const float4* W4 = reinterpret_cast<const float4*>(Wl);

    const int r = tid >> 5;   // 0..7  (row within group)
    const int c = tid & 31;   // 0..31 (float4 column)

    for (int g = 0; g < GROUPS; ++g) {
        const int rowbase = (blockIdx.x * GROUPS + g) * ROWS_PER_ITER;
        __syncthreads();  // xr free to overwrite
        for (int i = tid; i < ROWS_PER_ITER * D; i += 256) {
            const int row = rowbase + (i >> 7);
            float v = (row < n) ? X[(size_t)rowbase * D + i] : 0.0f;
            if (RELU) v = fmaxf(v, 0.0f);
            xr[i] = v;
        }
        __syncthreads();  // xr (and Wl, first time) visible

        const int row = rowbase + r;
        if (row < n) {
            float4 acc = make_float4(0.f, 0.f, 0.f, 0.f);
#pragma unroll 8
            for (int k = 0; k < D; ++k) {
                const float xv = xr[r * D + k];
                const float4 w = W4[k * 32 + c];
                acc.x += xv * w.x;
                acc.y += xv * w.y;
                acc.z += xv * w.z;
                acc.w += xv * w.w;
            }
            reinterpret_cast<float4*>(out)[(size_t)row * 32 + c] = acc;
        }
    }
}

// ---------------- aggregation ----------------
// init: out[i][f] = dis[i]^2 * h[i][f] + b[f]   (self-loop + bias, non-atomic)
__global__ void k_agg_init(const float* __restrict__ h, const float* __restrict__ dis,
                           const float* __restrict__ b, float* __restrict__ out, int n) {
    const long gid = (long)blockIdx.x * blockDim.x + threadIdx.x;
    if (gid < (long)n * D) {
        const int i = (int)(gid >> 7);
        const int f = (int)(gid & 127);
        const float w = dis[i];
        out[gid] = w * w * h[gid] + b[f];
    }
}

// edges: out[dst][f] += dis[src]*dis[dst] * h[src][f]
__global__ void k_agg_edges(const float* __restrict__ h, const int* __restrict__ src,
                            const int* __restrict__ dst, const float* __restrict__ dis,
                            float* __restrict__ out, int nE) {
    const long gid = (long)blockIdx.x * blockDim.x + threadIdx.x;
    const long e = gid >> 7;
    const int f = (int)(gid & 127);
    if (e < nE) {
        const int s = src[e];
        const int d = dst[e];
        const float w = dis[s] * dis[d];
        atomicAdd(&out[(size_t)d * D + f], w * h[(size_t)s * D + f]);
    }
}

extern "C" void kernel_launch(void* const* d_in, const int* in_sizes, int n_in,
                              void* d_out, int out_size, void* d_ws, size_t ws_size,
                              hipStream_t stream) {
    const float* x  = (const float*)d_in[0];
    const int*   ei = (const int*)d_in[1];   // [2, E] int32
    const float* W1 = (const float*)d_in[2];
    const float* b1 = (const float*)d_in[3];
    const float* W2 = (const float*)d_in[4];
    const float* b2 = (const float*)d_in[5];
    float* out = (float*)d_out;

    const int n  = in_sizes[0] / D;
    const int nE = in_sizes[1] / 2;
    const int* src = ei;
    const int* dst = ei + nE;

    char* ws = (char*)d_ws;
    float* dis = (float*)ws;                                  // n floats (~400KB)
    float* h   = (float*)(ws + (1ull << 20));                 // n*128 f32 (~48.8MiB)
    float* agg = (float*)(ws + (1ull << 20) + (50ull << 20)); // n*128 f32

    const int B = 256;
    // degrees (dst-based, incl. self loop), then rsqrt in place
    k_init_deg<<<(n + B - 1) / B, B, 0, stream>>>(dis, n);
    k_deg_edges<<<(nE + B - 1) / B, B, 0, stream>>>(dst, dis, nE);
    k_fin_deg<<<(n + B - 1) / B, B, 0, stream>>>(dis, n);

    const int gemm_grid = (n + ROWS_PER_BLOCK - 1) / ROWS_PER_BLOCK;
    const long nd = (long)n * D;
    const int agg_grid  = (int)((nd + B - 1) / B);
    const long ed = (long)nE * D;
    const int edge_grid = (int)((ed + B - 1) / B);

    // ---- layer 1 ----
    k_gemm<false><<<gemm_grid, B, 0, stream>>>(x, W1, h, n);
    k_agg_init<<<agg_grid, B, 0, stream>>>(h, dis, b1, agg, n);
    k_agg_edges<<<edge_grid, B, 0, stream>>>(h, src, dst, dis, agg, nE);

    // ---- layer 2 (ReLU fused into GEMM input read) ----
    k_gemm<true><<<gemm_grid, B, 0, stream>>>(agg, W2, h, n);
    k_agg_init<<<agg_grid, B, 0, stream>>>(h, dis, b2, out, n);
    k_agg_edges<<<edge_grid, B, 0, stream>>>(h, src, dst, dis, out, nE);
}

// Round 2
// 621.837 us; speedup vs baseline: 1.3344x; 1.3344x over previous
//
#include <hip/hip_runtime.h>

#define D 128

// ---------------- degree kernels ----------------
__global__ void k_init_deg(float* __restrict__ deg, int n) {
    int i = blockIdx.x * blockDim.x + threadIdx.x;
    if (i < n) deg[i] = 1.0f;  // self-loop contributes 1
}

__global__ void k_deg_edges(const int* __restrict__ dst, float* __restrict__ deg, int nE) {
    int e = blockIdx.x * blockDim.x + threadIdx.x;
    if (e < nE) atomicAdd(&deg[dst[e]], 1.0f);
}

__global__ void k_fin_deg(float* __restrict__ deg, int n) {
    int i = blockIdx.x * blockDim.x + threadIdx.x;
    if (i < n) deg[i] = rsqrtf(deg[i]);  // deg >= 1 always
}

// ---------------- CSR build (by dst) ----------------
__global__ void k_zero2(int* __restrict__ a, int* __restrict__ b, int n) {
    int i = blockIdx.x * blockDim.x + threadIdx.x;
    if (i < n) { a[i] = 0; b[i] = 0; }
}

__global__ void k_hist(const int* __restrict__ dst, int* __restrict__ counts, int nE) {
    int e = blockIdx.x * blockDim.x + threadIdx.x;
    if (e < nE) atomicAdd(&counts[dst[e]], 1);
}

// single-block exclusive scan of counts[0..n) -> starts[0..n]
__global__ __launch_bounds__(1024) void k_scan(const int* __restrict__ counts,
                                               int* __restrict__ starts, int n) {
    __shared__ int part[1024];
    const int t = threadIdx.x;
    const int chunk = (n + 1023) >> 10;
    const int lo = t * chunk;
    const int hi = min(lo + chunk, n);
    int s = 0;
    for (int i = lo; i < hi; ++i) s += counts[i];
    part[t] = s;
    __syncthreads();
    // Hillis-Steele inclusive scan over 1024 partials
    for (int off = 1; off < 1024; off <<= 1) {
        int v = (t >= off) ? part[t - off] : 0;
        __syncthreads();
        part[t] += v;
        __syncthreads();
    }
    int run = (t > 0) ? part[t - 1] : 0;
    for (int i = lo; i < hi; ++i) { starts[i] = run; run += counts[i]; }
    if (lo < n && hi == n) starts[n] = run;
}

__global__ void k_scatter(const int* __restrict__ src, const int* __restrict__ dst,
                          const int* __restrict__ starts, int* __restrict__ cursor,
                          int* __restrict__ esrc, int nE) {
    int e = blockIdx.x * blockDim.x + threadIdx.x;
    if (e < nE) {
        const int d = dst[e];
        const int p = starts[d] + atomicAdd(&cursor[d], 1);
        esrc[p] = src[e];
    }
}

// ---------------- GEMM: out[n,128] = (relu?)(X) @ W ----------------
#define ROWS_PER_ITER 8
#define GROUPS 8
#define ROWS_PER_BLOCK (ROWS_PER_ITER * GROUPS)

template <bool RELU>
__global__ __launch_bounds__(256) void k_gemm(const float* __restrict__ X,
                                              const float* __restrict__ W,
                                              float* __restrict__ out, int n) {
    __shared__ float Wl[D * D];              // 64 KB
    __shared__ float xr[ROWS_PER_ITER * D];  // 4 KB
    const int tid = threadIdx.x;

    for (int i = tid; i < D * D; i += 256) Wl[i] = W[i];
    const float4* W4 = reinterpret_cast<const float4*>(Wl);

    const int r = tid >> 5;   // 0..7  (row within group)
    const int c = tid & 31;   // 0..31 (float4 column)

    for (int g = 0; g < GROUPS; ++g) {
        const int rowbase = (blockIdx.x * GROUPS + g) * ROWS_PER_ITER;
        __syncthreads();  // xr free to overwrite
        for (int i = tid; i < ROWS_PER_ITER * D; i += 256) {
            const int row = rowbase + (i >> 7);
            float v = (row < n) ? X[(size_t)rowbase * D + i] : 0.0f;
            if (RELU) v = fmaxf(v, 0.0f);
            xr[i] = v;
        }
        __syncthreads();  // xr (and Wl, first time) visible

        const int row = rowbase + r;
        if (row < n) {
            float4 acc = make_float4(0.f, 0.f, 0.f, 0.f);
#pragma unroll 8
            for (int k = 0; k < D; ++k) {
                const float xv = xr[r * D + k];
                const float4 w = W4[k * 32 + c];
                acc.x += xv * w.x;
                acc.y += xv * w.y;
                acc.z += xv * w.z;
                acc.w += xv * w.w;
            }
            reinterpret_cast<float4*>(out)[(size_t)row * 32 + c] = acc;
        }
    }
}

// ---------------- gather-aggregate ----------------
// One wave per node: out[i] = dis[i]^2*h[i] + b + sum_{j in in(i)} dis[s]*dis[i]*h[s]
__global__ __launch_bounds__(256) void k_gather_agg(const float* __restrict__ h,
                                                    const int* __restrict__ starts,
                                                    const int* __restrict__ esrc,
                                                    const float* __restrict__ dis,
                                                    const float* __restrict__ b,
                                                    float* __restrict__ out, int n) {
    const int wave = threadIdx.x >> 6;          // 0..3
    const int lane = threadIdx.x & 63;
    const int i = blockIdx.x * 4 + wave;
    if (i >= n) return;

    const float2* h2 = reinterpret_cast<const float2*>(h);
    const float di = dis[i];
    const int beg = starts[i];
    const int end = starts[i + 1];

    float2 acc;
    {   // self loop + bias
        const float2 hv = h2[(size_t)i * 64 + lane];
        const float2 bv = reinterpret_cast<const float2*>(b)[lane];
        const float w = di * di;
        acc.x = w * hv.x + bv.x;
        acc.y = w * hv.y + bv.y;
    }

    int j = beg;
    for (; j + 1 < end; j += 2) {  // 2-deep for memory-level parallelism
        const int s0 = esrc[j];
        const int s1 = esrc[j + 1];
        const float w0 = dis[s0] * di;
        const float w1 = dis[s1] * di;
        const float2 a0 = h2[(size_t)s0 * 64 + lane];
        const float2 a1 = h2[(size_t)s1 * 64 + lane];
        acc.x += w0 * a0.x + w1 * a1.x;
        acc.y += w0 * a0.y + w1 * a1.y;
    }
    if (j < end) {
        const int s0 = esrc[j];
        const float w0 = dis[s0] * di;
        const float2 a0 = h2[(size_t)s0 * 64 + lane];
        acc.x += w0 * a0.x;
        acc.y += w0 * a0.y;
    }

    reinterpret_cast<float2*>(out)[(size_t)i * 64 + lane] = acc;
}

extern "C" void kernel_launch(void* const* d_in, const int* in_sizes, int n_in,
                              void* d_out, int out_size, void* d_ws, size_t ws_size,
                              hipStream_t stream) {
    const float* x  = (const float*)d_in[0];
    const int*   ei = (const int*)d_in[1];   // [2, E]
    const float* W1 = (const float*)d_in[2];
    const float* b1 = (const float*)d_in[3];
    const float* W2 = (const float*)d_in[4];
    const float* b2 = (const float*)d_in[5];
    float* out = (float*)d_out;

    const int n  = in_sizes[0] / D;
    const int nE = in_sizes[1] / 2;
    const int* src = ei;
    const int* dst = ei + nE;

    char* ws = (char*)d_ws;
    float* dis    = (float*)(ws);                   // n f32        (<512K)
    int*   counts = (int*)(ws + (1ull  << 19));     // n i32        (<512K)
    int*   starts = (int*)(ws + (2ull  << 19));     // n+1 i32      (<512K)
    int*   cursor = (int*)(ws + (3ull  << 19));     // n i32        (<512K)
    int*   esrc   = (int*)(ws + (4ull  << 19));     // nE i32       (~2.4M)
    float* h      = (float*)(ws + (8ull  << 20));   // n*128 f32    (~48.9M)
    float* agg    = (float*)(ws + (60ull << 20));   // n*128 f32    (~48.9M)

    const int B = 256;
    const int gn = (n + B - 1) / B;
    const int ge = (nE + B - 1) / B;

    // degrees (dst-based, incl. self loop) -> rsqrt
    k_init_deg<<<gn, B, 0, stream>>>(dis, n);
    k_deg_edges<<<ge, B, 0, stream>>>(dst, dis, nE);
    k_fin_deg<<<gn, B, 0, stream>>>(dis, n);

    // CSR by dst
    k_zero2<<<gn, B, 0, stream>>>(counts, cursor, n);
    k_hist<<<ge, B, 0, stream>>>(dst, counts, nE);
    k_scan<<<1, 1024, 0, stream>>>(counts, starts, n);
    k_scatter<<<ge, B, 0, stream>>>(src, dst, starts, cursor, esrc, nE);

    const int gemm_grid = (n + ROWS_PER_BLOCK - 1) / ROWS_PER_BLOCK;
    const int agg_grid = (n + 3) / 4;

    // ---- layer 1 ----
    k_gemm<false><<<gemm_grid, B, 0, stream>>>(x, W1, h, n);
    k_gather_agg<<<agg_grid, B, 0, stream>>>(h, starts, esrc, dis, b1, agg, n);

    // ---- layer 2 (ReLU fused into GEMM input read) ----
    k_gemm<true><<<gemm_grid, B, 0, stream>>>(agg, W2, h, n);
    k_gather_agg<<<agg_grid, B, 0, stream>>>(h, starts, esrc, dis, b2, out, n);
}

// Round 3
// 432.234 us; speedup vs baseline: 1.9198x; 1.4387x over previous
//
#include <hip/hip_runtime.h>

#define D 128

// ---------------- CSR build (by dst) ----------------
__global__ void k_zero2(int* __restrict__ a, int* __restrict__ b, int n) {
    int i = blockIdx.x * blockDim.x + threadIdx.x;
    if (i < n) { a[i] = 0; b[i] = 0; }
}

__global__ void k_hist(const int* __restrict__ dst, int* __restrict__ counts, int nE) {
    int e = blockIdx.x * blockDim.x + threadIdx.x;
    if (e < nE) atomicAdd(&counts[dst[e]], 1);
}

// Pass 1: per-block (1024-element tile) sums of counts; fused dis = rsqrt(counts+1).
__global__ __launch_bounds__(256) void k_scan_part(const int* __restrict__ counts,
                                                   int* __restrict__ bsum,
                                                   float* __restrict__ dis, int n) {
    const int t = threadIdx.x;
    const int base = blockIdx.x * 1024 + t * 4;
    int4 c = make_int4(0, 0, 0, 0);
    if (base + 4 <= n) {
        c = *reinterpret_cast<const int4*>(counts + base);
        float4 dv;
        dv.x = rsqrtf((float)(c.x + 1));
        dv.y = rsqrtf((float)(c.y + 1));
        dv.z = rsqrtf((float)(c.z + 1));
        dv.w = rsqrtf((float)(c.w + 1));
        *reinterpret_cast<float4*>(dis + base) = dv;
    } else if (base < n) {
        int cc[4] = {0, 0, 0, 0};
        for (int k = 0; k < 4; ++k)
            if (base + k < n) {
                cc[k] = counts[base + k];
                dis[base + k] = rsqrtf((float)(cc[k] + 1));
            }
        c.x = cc[0]; c.y = cc[1]; c.z = cc[2]; c.w = cc[3];
    }
    __shared__ int red[256];
    red[t] = c.x + c.y + c.z + c.w;
    __syncthreads();
    for (int off = 128; off > 0; off >>= 1) {
        if (t < off) red[t] += red[t + off];
        __syncthreads();
    }
    if (t == 0) bsum[blockIdx.x] = red[0];
}

// Pass 2: each block scans the (<=128) block sums in LDS, then local-scans its
// 1024-count tile and writes exclusive prefix to starts. Block 0 writes starts[n].
__global__ __launch_bounds__(256) void k_scan_final(const int* __restrict__ counts,
                                                    const int* __restrict__ bsum,
                                                    int* __restrict__ starts, int n, int nB) {
    __shared__ int sb[128];
    __shared__ int ts[256];
    const int t = threadIdx.x;
    const int b = blockIdx.x;

    // scan of block sums (nB <= 128 for n <= 131072)
    if (t < 128) sb[t] = (t < nB) ? bsum[t] : 0;
    __syncthreads();
    for (int off = 1; off < 128; off <<= 1) {
        int add = (t < 128 && t >= off) ? sb[t - off] : 0;
        __syncthreads();
        if (t < 128) sb[t] += add;
        __syncthreads();
    }
    const int block_off = (b > 0) ? sb[b - 1] : 0;

    // local tile
    const int base = b * 1024 + t * 4;
    int4 c = make_int4(0, 0, 0, 0);
    if (base + 4 <= n) {
        c = *reinterpret_cast<const int4*>(counts + base);
    } else if (base < n) {
        if (base + 0 < n) c.x = counts[base + 0];
        if (base + 1 < n) c.y = counts[base + 1];
        if (base + 2 < n) c.z = counts[base + 2];
    }
    const int s = c.x + c.y + c.z + c.w;
    ts[t] = s;
    __syncthreads();
    for (int off = 1; off < 256; off <<= 1) {
        int add = (t >= off) ? ts[t - off] : 0;
        __syncthreads();
        ts[t] += add;
        __syncthreads();
    }
    int excl = block_off + ts[t] - s;

    int4 w;
    w.x = excl;
    w.y = w.x + c.x;
    w.z = w.y + c.y;
    w.w = w.z + c.z;
    if (base + 4 <= n) {
        *reinterpret_cast<int4*>(starts + base) = w;
    } else if (base < n) {
        if (base + 0 < n) starts[base + 0] = w.x;
        if (base + 1 < n) starts[base + 1] = w.y;
        if (base + 2 < n) starts[base + 2] = w.z;
    }
    if (b == 0 && t == 0) starts[n] = sb[nB - 1];  // = nE
}

__global__ void k_scatter(const int* __restrict__ src, const int* __restrict__ dst,
                          const int* __restrict__ starts, int* __restrict__ cursor,
                          int* __restrict__ esrc, int nE) {
    int e = blockIdx.x * blockDim.x + threadIdx.x;
    if (e < nE) {
        const int d = dst[e];
        const int p = starts[d] + atomicAdd(&cursor[d], 1);
        esrc[p] = src[e];
    }
}

// ---------------- GEMM: out[n,128] = (relu?)(X) @ W ----------------
#define ROWS_PER_ITER 8
#define GROUPS 8
#define ROWS_PER_BLOCK (ROWS_PER_ITER * GROUPS)

template <bool RELU>
__global__ __launch_bounds__(256) void k_gemm(const float* __restrict__ X,
                                              const float* __restrict__ W,
                                              float* __restrict__ out, int n) {
    __shared__ float Wl[D * D];              // 64 KB
    __shared__ float xr[ROWS_PER_ITER * D];  // 4 KB
    const int tid = threadIdx.x;

    for (int i = tid; i < D * D; i += 256) Wl[i] = W[i];
    const float4* W4 = reinterpret_cast<const float4*>(Wl);

    const int r = tid >> 5;   // 0..7  (row within group)
    const int c = tid & 31;   // 0..31 (float4 column)

    for (int g = 0; g < GROUPS; ++g) {
        const int rowbase = (blockIdx.x * GROUPS + g) * ROWS_PER_ITER;
        __syncthreads();  // xr free to overwrite
        for (int i = tid; i < ROWS_PER_ITER * D; i += 256) {
            const int row = rowbase + (i >> 7);
            float v = (row < n) ? X[(size_t)rowbase * D + i] : 0.0f;
            if (RELU) v = fmaxf(v, 0.0f);
            xr[i] = v;
        }
        __syncthreads();  // xr (and Wl, first time) visible

        const int row = rowbase + r;
        if (row < n) {
            float4 acc = make_float4(0.f, 0.f, 0.f, 0.f);
#pragma unroll 8
            for (int k = 0; k < D; ++k) {
                const float xv = xr[r * D + k];
                const float4 w = W4[k * 32 + c];
                acc.x += xv * w.x;
                acc.y += xv * w.y;
                acc.z += xv * w.z;
                acc.w += xv * w.w;
            }
            reinterpret_cast<float4*>(out)[(size_t)row * 32 + c] = acc;
        }
    }
}

// ---------------- gather-aggregate ----------------
// One wave per node: out[i] = dis[i]^2*h[i] + b + sum_{j in in(i)} dis[s]*dis[i]*h[s]
__global__ __launch_bounds__(256) void k_gather_agg(const float* __restrict__ h,
                                                    const int* __restrict__ starts,
                                                    const int* __restrict__ esrc,
                                                    const float* __restrict__ dis,
                                                    const float* __restrict__ b,
                                                    float* __restrict__ out, int n) {
    const int wave = threadIdx.x >> 6;  // 0..3
    const int lane = threadIdx.x & 63;
    const int i = blockIdx.x * 4 + wave;
    if (i >= n) return;

    const float2* h2 = reinterpret_cast<const float2*>(h);
    const float di = dis[i];
    const int beg = starts[i];
    const int end = starts[i + 1];

    float2 acc;
    {   // self loop + bias
        const float2 hv = h2[(size_t)i * 64 + lane];
        const float2 bv = reinterpret_cast<const float2*>(b)[lane];
        const float w = di * di;
        acc.x = w * hv.x + bv.x;
        acc.y = w * hv.y + bv.y;
    }

    int j = beg;
    for (; j + 1 < end; j += 2) {  // 2-deep for memory-level parallelism
        const int s0 = esrc[j];
        const int s1 = esrc[j + 1];
        const float w0 = dis[s0] * di;
        const float w1 = dis[s1] * di;
        const float2 a0 = h2[(size_t)s0 * 64 + lane];
        const float2 a1 = h2[(size_t)s1 * 64 + lane];
        acc.x += w0 * a0.x + w1 * a1.x;
        acc.y += w0 * a0.y + w1 * a1.y;
    }
    if (j < end) {
        const int s0 = esrc[j];
        const float w0 = dis[s0] * di;
        const float2 a0 = h2[(size_t)s0 * 64 + lane];
        acc.x += w0 * a0.x;
        acc.y += w0 * a0.y;
    }

    reinterpret_cast<float2*>(out)[(size_t)i * 64 + lane] = acc;
}

extern "C" void kernel_launch(void* const* d_in, const int* in_sizes, int n_in,
                              void* d_out, int out_size, void* d_ws, size_t ws_size,
                              hipStream_t stream) {
    const float* x  = (const float*)d_in[0];
    const int*   ei = (const int*)d_in[1];   // [2, E]
    const float* W1 = (const float*)d_in[2];
    const float* b1 = (const float*)d_in[3];
    const float* W2 = (const float*)d_in[4];
    const float* b2 = (const float*)d_in[5];
    float* out = (float*)d_out;

    const int n  = in_sizes[0] / D;
    const int nE = in_sizes[1] / 2;
    const int* src = ei;
    const int* dst = ei + nE;

    char* ws = (char*)d_ws;
    float* dis    = (float*)(ws);                   // n f32        (<512K)
    int*   counts = (int*)(ws + (1ull  << 19));     // n i32        (<512K)
    int*   starts = (int*)(ws + (2ull  << 19));     // n+1 i32      (<512K)
    int*   cursor = (int*)(ws + (3ull  << 19));     // n i32        (<512K)
    int*   esrc   = (int*)(ws + (4ull  << 19));     // nE i32       (~2.4M)
    int*   bsum   = (int*)(ws + (6ull  << 20));     // <=128 i32
    float* h      = (float*)(ws + (8ull  << 20));   // n*128 f32    (~48.9M)
    float* agg    = (float*)(ws + (60ull << 20));   // n*128 f32    (~48.9M)

    const int B = 256;
    const int gn = (n + B - 1) / B;
    const int ge = (nE + B - 1) / B;
    const int nB = (n + 1023) / 1024;  // <=128 for n<=131072

    // CSR by dst (counts also yields degrees: deg = counts + 1 self-loop)
    k_zero2<<<gn, B, 0, stream>>>(counts, cursor, n);
    k_hist<<<ge, B, 0, stream>>>(dst, counts, nE);
    k_scan_part<<<nB, B, 0, stream>>>(counts, bsum, dis, n);
    k_scan_final<<<nB, B, 0, stream>>>(counts, bsum, starts, n, nB);
    k_scatter<<<ge, B, 0, stream>>>(src, dst, starts, cursor, esrc, nE);

    const int gemm_grid = (n + ROWS_PER_BLOCK - 1) / ROWS_PER_BLOCK;
    const int agg_grid = (n + 3) / 4;

    // ---- layer 1 ----
    k_gemm<false><<<gemm_grid, B, 0, stream>>>(x, W1, h, n);
    k_gather_agg<<<agg_grid, B, 0, stream>>>(h, starts, esrc, dis, b1, agg, n);

    // ---- layer 2 (ReLU fused into GEMM input read) ----
    k_gemm<true><<<gemm_grid, B, 0, stream>>>(agg, W2, h, n);
    k_gather_agg<<<agg_grid, B, 0, stream>>>(h, starts, esrc, dis, b2, out, n);
}

// Round 4
// 313.864 us; speedup vs baseline: 2.6438x; 1.3771x over previous
//
#include <hip/hip_runtime.h>

#define D 128

typedef __attribute__((ext_vector_type(8))) short bf16x8;
typedef __attribute__((ext_vector_type(4))) float f32x4;

__device__ inline short f2bf(float f) {  // RNE fp32->bf16
    unsigned u = __builtin_bit_cast(unsigned, f);
    u += 0x7FFFu + ((u >> 16) & 1u);
    return (short)(u >> 16);
}

// ---------------- CSR build (by dst) ----------------
__global__ void k_zero2(int* __restrict__ a, int* __restrict__ b, int n) {
    int i = blockIdx.x * blockDim.x + threadIdx.x;
    if (i < n) { a[i] = 0; b[i] = 0; }
}

__global__ void k_hist(const int* __restrict__ dst, int* __restrict__ counts, int nE) {
    int e = blockIdx.x * blockDim.x + threadIdx.x;
    if (e < nE) atomicAdd(&counts[dst[e]], 1);
}

// Pass 1: per-block (1024-element tile) sums of counts; fused dis = rsqrt(counts+1).
__global__ __launch_bounds__(256) void k_scan_part(const int* __restrict__ counts,
                                                   int* __restrict__ bsum,
                                                   float* __restrict__ dis, int n) {
    const int t = threadIdx.x;
    const int base = blockIdx.x * 1024 + t * 4;
    int4 c = make_int4(0, 0, 0, 0);
    if (base + 4 <= n) {
        c = *reinterpret_cast<const int4*>(counts + base);
        float4 dv;
        dv.x = rsqrtf((float)(c.x + 1));
        dv.y = rsqrtf((float)(c.y + 1));
        dv.z = rsqrtf((float)(c.z + 1));
        dv.w = rsqrtf((float)(c.w + 1));
        *reinterpret_cast<float4*>(dis + base) = dv;
    } else if (base < n) {
        int cc[4] = {0, 0, 0, 0};
        for (int k = 0; k < 4; ++k)
            if (base + k < n) {
                cc[k] = counts[base + k];
                dis[base + k] = rsqrtf((float)(cc[k] + 1));
            }
        c.x = cc[0]; c.y = cc[1]; c.z = cc[2]; c.w = cc[3];
    }
    __shared__ int red[256];
    red[t] = c.x + c.y + c.z + c.w;
    __syncthreads();
    for (int off = 128; off > 0; off >>= 1) {
        if (t < off) red[t] += red[t + off];
        __syncthreads();
    }
    if (t == 0) bsum[blockIdx.x] = red[0];
}

// Pass 2: each block scans the (<=128) block sums in LDS, then local-scans its
// 1024-count tile and writes exclusive prefix to starts. Block 0 writes starts[n].
__global__ __launch_bounds__(256) void k_scan_final(const int* __restrict__ counts,
                                                    const int* __restrict__ bsum,
                                                    int* __restrict__ starts, int n, int nB) {
    __shared__ int sb[128];
    __shared__ int ts[256];
    const int t = threadIdx.x;
    const int b = blockIdx.x;

    if (t < 128) sb[t] = (t < nB) ? bsum[t] : 0;
    __syncthreads();
    for (int off = 1; off < 128; off <<= 1) {
        int add = (t < 128 && t >= off) ? sb[t - off] : 0;
        __syncthreads();
        if (t < 128) sb[t] += add;
        __syncthreads();
    }
    const int block_off = (b > 0) ? sb[b - 1] : 0;

    const int base = b * 1024 + t * 4;
    int4 c = make_int4(0, 0, 0, 0);
    if (base + 4 <= n) {
        c = *reinterpret_cast<const int4*>(counts + base);
    } else if (base < n) {
        if (base + 0 < n) c.x = counts[base + 0];
        if (base + 1 < n) c.y = counts[base + 1];
        if (base + 2 < n) c.z = counts[base + 2];
    }
    const int s = c.x + c.y + c.z + c.w;
    ts[t] = s;
    __syncthreads();
    for (int off = 1; off < 256; off <<= 1) {
        int add = (t >= off) ? ts[t - off] : 0;
        __syncthreads();
        ts[t] += add;
        __syncthreads();
    }
    int excl = block_off + ts[t] - s;

    int4 w;
    w.x = excl;
    w.y = w.x + c.x;
    w.z = w.y + c.y;
    w.w = w.z + c.z;
    if (base + 4 <= n) {
        *reinterpret_cast<int4*>(starts + base) = w;
    } else if (base < n) {
        if (base + 0 < n) starts[base + 0] = w.x;
        if (base + 1 < n) starts[base + 1] = w.y;
        if (base + 2 < n) starts[base + 2] = w.z;
    }
    if (b == 0 && t == 0) starts[n] = sb[nB - 1];  // = nE
}

__global__ void k_scatter(const int* __restrict__ src, const int* __restrict__ dst,
                          const int* __restrict__ starts, int* __restrict__ cursor,
                          int* __restrict__ esrc, int nE) {
    int e = blockIdx.x * blockDim.x + threadIdx.x;
    if (e < nE) {
        const int d = dst[e];
        const int p = starts[d] + atomicAdd(&cursor[d], 1);
        esrc[p] = src[e];
    }
}

// ---------------- MFMA GEMM: out[n,128] = (relu?)(X) @ W ----------------
// Each wave: all of W held as 32 bf16 B-fragments in regs (loaded once from L2).
// Grid-stride over 16-row tiles: 8 global dwordx4 A-loads (prefetched), 32 MFMA,
// 32 stores. No LDS, no barriers.
// Fragment layouts (HW-verified, learn_hip m89/m92/m97):
//   A: row = lane&15, k = 8*(lane>>4)+e   (8 consecutive k per lane)
//   B: col = lane&15, k = 8*(lane>>4)+e
//   D: col = lane&15, row = 4*(lane>>4)+reg
template <bool RELU>
__global__ __launch_bounds__(256, 2) void k_gemm_mfma(const float* __restrict__ X,
                                                      const float* __restrict__ W,
                                                      float* __restrict__ out,
                                                      int n, int ntiles) {
    const int lane = threadIdx.x & 63;
    const int col16 = lane & 15;
    const int kgrp = lane >> 4;

    // ---- W -> 32 register B-fragments (bw[ct][kk]), bf16 ----
    bf16x8 bw[8][4];
#pragma unroll
    for (int ct = 0; ct < 8; ++ct)
#pragma unroll
        for (int kk = 0; kk < 4; ++kk)
#pragma unroll
            for (int e = 0; e < 8; ++e) {
                const int k = kk * 32 + kgrp * 8 + e;
                bw[ct][kk][e] = f2bf(W[k * D + ct * 16 + col16]);
            }

    const int gwave = (blockIdx.x * blockDim.x + threadIdx.x) >> 6;
    const int nwaves = (gridDim.x * blockDim.x) >> 6;

    float4 p[8];
    auto load_tile = [&](int tile) {
        int arow = tile * 16 + col16;
        if (arow >= n) arow = n - 1;  // tail clamp; masked at store
        const float4* Xr = reinterpret_cast<const float4*>(X + (size_t)arow * D);
#pragma unroll
        for (int kk = 0; kk < 4; ++kk) {
            p[kk * 2 + 0] = Xr[kk * 8 + kgrp * 2 + 0];
            p[kk * 2 + 1] = Xr[kk * 8 + kgrp * 2 + 1];
        }
    };

    if (gwave < ntiles) load_tile(gwave);

    for (int tile = gwave; tile < ntiles; tile += nwaves) {
        // convert current tile's A to bf16 fragments
        bf16x8 a[4];
#pragma unroll
        for (int kk = 0; kk < 4; ++kk) {
            float v[8] = {p[kk * 2].x, p[kk * 2].y, p[kk * 2].z, p[kk * 2].w,
                          p[kk * 2 + 1].x, p[kk * 2 + 1].y, p[kk * 2 + 1].z, p[kk * 2 + 1].w};
#pragma unroll
            for (int e = 0; e < 8; ++e) {
                float f = v[e];
                if (RELU) f = fmaxf(f, 0.0f);
                a[kk][e] = f2bf(f);
            }
        }
        // prefetch next tile while MFMAs run
        const int next = tile + nwaves;
        if (next < ntiles) load_tile(next);

        f32x4 acc[8];
#pragma unroll
        for (int ct = 0; ct < 8; ++ct) acc[ct] = (f32x4){0.f, 0.f, 0.f, 0.f};
#pragma unroll
        for (int kk = 0; kk < 4; ++kk)
#pragma unroll
            for (int ct = 0; ct < 8; ++ct)
                acc[ct] = __builtin_amdgcn_mfma_f32_16x16x32_bf16(a[kk], bw[ct][kk], acc[ct], 0, 0, 0);

        const int rowbase = tile * 16;
#pragma unroll
        for (int ct = 0; ct < 8; ++ct)
#pragma unroll
            for (int r = 0; r < 4; ++r) {
                const int row = rowbase + kgrp * 4 + r;
                if (row < n) out[(size_t)row * D + ct * 16 + col16] = acc[ct][r];
            }
    }
}

// ---------------- gather-aggregate ----------------
// One wave per node: out[i] = dis[i]^2*h[i] + b + sum_{j in in(i)} dis[s]*dis[i]*h[s]
__global__ __launch_bounds__(256) void k_gather_agg(const float* __restrict__ h,
                                                    const int* __restrict__ starts,
                                                    const int* __restrict__ esrc,
                                                    const float* __restrict__ dis,
                                                    const float* __restrict__ b,
                                                    float* __restrict__ out, int n) {
    const int wave = threadIdx.x >> 6;  // 0..3
    const int lane = threadIdx.x & 63;
    const int i = blockIdx.x * 4 + wave;
    if (i >= n) return;

    const float2* h2 = reinterpret_cast<const float2*>(h);
    const float di = dis[i];
    const int beg = starts[i];
    const int end = starts[i + 1];

    float2 acc;
    {   // self loop + bias
        const float2 hv = h2[(size_t)i * 64 + lane];
        const float2 bv = reinterpret_cast<const float2*>(b)[lane];
        const float w = di * di;
        acc.x = w * hv.x + bv.x;
        acc.y = w * hv.y + bv.y;
    }

    int j = beg;
    for (; j + 1 < end; j += 2) {  // 2-deep for memory-level parallelism
        const int s0 = esrc[j];
        const int s1 = esrc[j + 1];
        const float w0 = dis[s0] * di;
        const float w1 = dis[s1] * di;
        const float2 a0 = h2[(size_t)s0 * 64 + lane];
        const float2 a1 = h2[(size_t)s1 * 64 + lane];
        acc.x += w0 * a0.x + w1 * a1.x;
        acc.y += w0 * a0.y + w1 * a1.y;
    }
    if (j < end) {
        const int s0 = esrc[j];
        const float w0 = dis[s0] * di;
        const float2 a0 = h2[(size_t)s0 * 64 + lane];
        acc.x += w0 * a0.x;
        acc.y += w0 * a0.y;
    }

    reinterpret_cast<float2*>(out)[(size_t)i * 64 + lane] = acc;
}

extern "C" void kernel_launch(void* const* d_in, const int* in_sizes, int n_in,
                              void* d_out, int out_size, void* d_ws, size_t ws_size,
                              hipStream_t stream) {
    const float* x  = (const float*)d_in[0];
    const int*   ei = (const int*)d_in[1];   // [2, E]
    const float* W1 = (const float*)d_in[2];
    const float* b1 = (const float*)d_in[3];
    const float* W2 = (const float*)d_in[4];
    const float* b2 = (const float*)d_in[5];
    float* out = (float*)d_out;

    const int n  = in_sizes[0] / D;
    const int nE = in_sizes[1] / 2;
    const int* src = ei;
    const int* dst = ei + nE;

    char* ws = (char*)d_ws;
    float* dis    = (float*)(ws);                   // n f32        (<512K)
    int*   counts = (int*)(ws + (1ull  << 19));     // n i32        (<512K)
    int*   starts = (int*)(ws + (2ull  << 19));     // n+1 i32      (<512K)
    int*   cursor = (int*)(ws + (3ull  << 19));     // n i32        (<512K)
    int*   esrc   = (int*)(ws + (4ull  << 19));     // nE i32       (~2.4M)
    int*   bsum   = (int*)(ws + (6ull  << 20));     // <=128 i32
    float* h      = (float*)(ws + (8ull  << 20));   // n*128 f32    (~48.9M)
    float* agg    = (float*)(ws + (60ull << 20));   // n*128 f32    (~48.9M)

    const int B = 256;
    const int gn = (n + B - 1) / B;
    const int ge = (nE + B - 1) / B;
    const int nB = (n + 1023) / 1024;  // <=128 for n<=131072

    // CSR by dst (counts also yields degrees: deg = counts + 1 self-loop)
    k_zero2<<<gn, B, 0, stream>>>(counts, cursor, n);
    k_hist<<<ge, B, 0, stream>>>(dst, counts, nE);
    k_scan_part<<<nB, B, 0, stream>>>(counts, bsum, dis, n);
    k_scan_final<<<nB, B, 0, stream>>>(counts, bsum, starts, n, nB);
    k_scatter<<<ge, B, 0, stream>>>(src, dst, starts, cursor, esrc, nE);

    const int ntiles = (n + 15) / 16;
    const int gemm_blocks = 512;  // 2 blocks/CU at 256 thr, VGPR-capped occupancy
    const int agg_grid = (n + 3) / 4;

    // ---- layer 1 ----
    k_gemm_mfma<false><<<gemm_blocks, B, 0, stream>>>(x, W1, h, n, ntiles);
    k_gather_agg<<<agg_grid, B, 0, stream>>>(h, starts, esrc, dis, b1, agg, n);

    // ---- layer 2 (ReLU fused into GEMM A-load) ----
    k_gemm_mfma<true><<<gemm_blocks, B, 0, stream>>>(agg, W2, h, n, ntiles);
    k_gather_agg<<<agg_grid, B, 0, stream>>>(h, starts, esrc, dis, b2, out, n);
}

// Round 5
// 207.480 us; speedup vs baseline: 3.9994x; 1.5127x over previous
//
#include <hip/hip_runtime.h>

#define D 128

typedef __attribute__((ext_vector_type(8))) short bf16x8;
typedef __attribute__((ext_vector_type(4))) float f32x4;

__device__ inline unsigned short f2bf(float f) {  // RNE fp32->bf16
    unsigned u = __builtin_bit_cast(unsigned, f);
    u += 0x7FFFu + ((u >> 16) & 1u);
    return (unsigned short)(u >> 16);
}
__device__ inline float bf_lo(unsigned u) { return __builtin_bit_cast(float, u << 16); }
__device__ inline float bf_hi(unsigned u) { return __builtin_bit_cast(float, u & 0xFFFF0000u); }

// ---------------- CSR build (by dst) ----------------
__global__ void k_zero1(int* __restrict__ a, int n) {
    int i = blockIdx.x * blockDim.x + threadIdx.x;
    if (i < n) a[i] = 0;
}

__global__ void k_hist(const int* __restrict__ dst, int* __restrict__ counts, int nE) {
    int e = blockIdx.x * blockDim.x + threadIdx.x;
    if (e < nE) atomicAdd(&counts[dst[e]], 1);
}

// Pass 1: per-block (1024-element tile) sums; fused dis = rsqrt(counts+1).
__global__ __launch_bounds__(256) void k_scan_part(const int* __restrict__ counts,
                                                   int* __restrict__ bsum,
                                                   float* __restrict__ dis, int n) {
    const int t = threadIdx.x;
    const int base = blockIdx.x * 1024 + t * 4;
    int4 c = make_int4(0, 0, 0, 0);
    if (base + 4 <= n) {
        c = *reinterpret_cast<const int4*>(counts + base);
        float4 dv;
        dv.x = rsqrtf((float)(c.x + 1));
        dv.y = rsqrtf((float)(c.y + 1));
        dv.z = rsqrtf((float)(c.z + 1));
        dv.w = rsqrtf((float)(c.w + 1));
        *reinterpret_cast<float4*>(dis + base) = dv;
    } else if (base < n) {
        int cc[4] = {0, 0, 0, 0};
        for (int k = 0; k < 4; ++k)
            if (base + k < n) {
                cc[k] = counts[base + k];
                dis[base + k] = rsqrtf((float)(cc[k] + 1));
            }
        c.x = cc[0]; c.y = cc[1]; c.z = cc[2]; c.w = cc[3];
    }
    __shared__ int red[256];
    red[t] = c.x + c.y + c.z + c.w;
    __syncthreads();
    for (int off = 128; off > 0; off >>= 1) {
        if (t < off) red[t] += red[t + off];
        __syncthreads();
    }
    if (t == 0) bsum[blockIdx.x] = red[0];
}

// Pass 2: scan block sums in LDS, local-scan tile, write starts AND cursor copy.
__global__ __launch_bounds__(256) void k_scan_final(const int* __restrict__ counts,
                                                    const int* __restrict__ bsum,
                                                    int* __restrict__ starts,
                                                    int* __restrict__ cursor, int n, int nB) {
    __shared__ int sb[128];
    __shared__ int ts[256];
    const int t = threadIdx.x;
    const int b = blockIdx.x;

    if (t < 128) sb[t] = (t < nB) ? bsum[t] : 0;
    __syncthreads();
    for (int off = 1; off < 128; off <<= 1) {
        int add = (t < 128 && t >= off) ? sb[t - off] : 0;
        __syncthreads();
        if (t < 128) sb[t] += add;
        __syncthreads();
    }
    const int block_off = (b > 0) ? sb[b - 1] : 0;

    const int base = b * 1024 + t * 4;
    int4 c = make_int4(0, 0, 0, 0);
    if (base + 4 <= n) {
        c = *reinterpret_cast<const int4*>(counts + base);
    } else if (base < n) {
        if (base + 0 < n) c.x = counts[base + 0];
        if (base + 1 < n) c.y = counts[base + 1];
        if (base + 2 < n) c.z = counts[base + 2];
    }
    const int s = c.x + c.y + c.z + c.w;
    ts[t] = s;
    __syncthreads();
    for (int off = 1; off < 256; off <<= 1) {
        int add = (t >= off) ? ts[t - off] : 0;
        __syncthreads();
        ts[t] += add;
        __syncthreads();
    }
    int excl = block_off + ts[t] - s;

    int4 w;
    w.x = excl;
    w.y = w.x + c.x;
    w.z = w.y + c.y;
    w.w = w.z + c.z;
    if (base + 4 <= n) {
        *reinterpret_cast<int4*>(starts + base) = w;
        *reinterpret_cast<int4*>(cursor + base) = w;
    } else if (base < n) {
        if (base + 0 < n) { starts[base + 0] = w.x; cursor[base + 0] = w.x; }
        if (base + 1 < n) { starts[base + 1] = w.y; cursor[base + 1] = w.y; }
        if (base + 2 < n) { starts[base + 2] = w.z; cursor[base + 2] = w.z; }
    }
    if (b == 0 && t == 0) starts[n] = sb[nB - 1];  // = nE
}

__global__ void k_scatter(const int* __restrict__ src, const int* __restrict__ dst,
                          int* __restrict__ cursor, int* __restrict__ esrc, int nE) {
    int e = blockIdx.x * blockDim.x + threadIdx.x;
    if (e < nE) {
        const int p = atomicAdd(&cursor[dst[e]], 1);
        esrc[p] = src[e];
    }
}

// ---------------- MFMA GEMM: out_bf16[n,128] = (relu?)(X) @ W ----------------
// W held per-wave as 32 bf16 B-fragments in regs. A staged per 64-row supertile
// through XOR-swizzled LDS (coalesced global reads, conflict-free ds_read_b128).
// Fragment layouts (verified by R4 pass): A row=lane&15, k=kk*32+kgrp*8+e;
// B col=lane&15 same k; D col=lane&15, row=kgrp*4+reg.
template <bool IN_BF16, bool RELU>
__global__ __launch_bounds__(256, 2) void k_gemm_mfma(const void* __restrict__ Xv,
                                                      const float* __restrict__ W,
                                                      unsigned short* __restrict__ outbf,
                                                      int n, int nst) {
    __shared__ __align__(16) unsigned short At[64 * 128];  // 16KB, swizzled
    const int tid = threadIdx.x;
    const int lane = tid & 63;
    const int wv = tid >> 6;
    const int col16 = lane & 15;
    const int kgrp = lane >> 4;

    // ---- W -> 32 register B-fragments ----
    bf16x8 bw[8][4];
#pragma unroll
    for (int ct = 0; ct < 8; ++ct)
#pragma unroll
        for (int kk = 0; kk < 4; ++kk)
#pragma unroll
            for (int e = 0; e < 8; ++e) {
                const int k = kk * 32 + kgrp * 8 + e;
                bw[ct][kk][e] = (short)f2bf(W[k * D + ct * 16 + col16]);
            }

    for (int st = blockIdx.x; st < nst; st += gridDim.x) {
        __syncthreads();  // prior compute done reading At
        // ---- stage 64x128 supertile to LDS (bf16, elem-swizzle col ^ ((row&7)<<3)) ----
#pragma unroll
        for (int c = 0; c < 4; ++c) {
            const int idx = c * 2048 + tid * 8;  // 8 consecutive elems per thread
            const int row = idx >> 7;
            const int col = idx & 127;
            int grow = st * 64 + row;
            if (grow >= n) grow = n - 1;  // clamp reads; stores masked
            bf16x8 d;
            if constexpr (IN_BF16) {
                d = *reinterpret_cast<const bf16x8*>(
                        (const unsigned short*)Xv + (size_t)grow * D + col);
                if (RELU) {
#pragma unroll
                    for (int e = 0; e < 8; ++e)
                        d[e] = (short)((d[e] & (short)0x8000) ? 0 : d[e]);
                }
            } else {
                const float4* p = reinterpret_cast<const float4*>(
                        (const float*)Xv + (size_t)grow * D + col);
                const float4 f0 = p[0], f1 = p[1];
                float v[8] = {f0.x, f0.y, f0.z, f0.w, f1.x, f1.y, f1.z, f1.w};
#pragma unroll
                for (int e = 0; e < 8; ++e) {
                    float f = v[e];
                    if (RELU) f = fmaxf(f, 0.0f);
                    d[e] = (short)f2bf(f);
                }
            }
            const int waddr = row * 128 + (col ^ ((row & 7) << 3));
            *reinterpret_cast<bf16x8*>(&At[waddr]) = d;
        }
        __syncthreads();

        // ---- compute: wave wv handles rows wv*16..wv*16+15 ----
        bf16x8 a[4];
#pragma unroll
        for (int kk = 0; kk < 4; ++kk) {
            const int raddr = (wv * 16 + col16) * 128 +
                              ((kk * 32 + kgrp * 8) ^ ((col16 & 7) << 3));
            a[kk] = *reinterpret_cast<const bf16x8*>(&At[raddr]);
        }

        f32x4 acc[8];
#pragma unroll
        for (int ct = 0; ct < 8; ++ct) acc[ct] = (f32x4){0.f, 0.f, 0.f, 0.f};
#pragma unroll
        for (int kk = 0; kk < 4; ++kk)
#pragma unroll
            for (int ct = 0; ct < 8; ++ct)
                acc[ct] = __builtin_amdgcn_mfma_f32_16x16x32_bf16(a[kk], bw[ct][kk], acc[ct], 0, 0, 0);

        const int rowbase = st * 64 + wv * 16;
#pragma unroll
        for (int ct = 0; ct < 8; ++ct)
#pragma unroll
            for (int r = 0; r < 4; ++r) {
                const int row = rowbase + kgrp * 4 + r;
                if (row < n) outbf[(size_t)row * D + ct * 16 + col16] = f2bf(acc[ct][r]);
            }
    }
}

// ---------------- gather-aggregate (bf16 h, fp32 accumulate) ----------------
// One wave per node: out[i] = dis[i]^2*h[i] + b + sum_{j in in(i)} dis[s]*dis[i]*h[s]
template <bool OUT_BF16>
__global__ __launch_bounds__(256) void k_gather_agg(const unsigned short* __restrict__ hbf,
                                                    const int* __restrict__ starts,
                                                    const int* __restrict__ esrc,
                                                    const float* __restrict__ dis,
                                                    const float* __restrict__ b,
                                                    void* __restrict__ outv, int n) {
    const int wv = threadIdx.x >> 6;  // 0..3
    const int lane = threadIdx.x & 63;
    const int i = blockIdx.x * 4 + wv;
    if (i >= n) return;

    const unsigned* h32 = reinterpret_cast<const unsigned*>(hbf);  // 2 bf16 per load
    const float di = dis[i];
    const int beg = starts[i];
    const int end = starts[i + 1];

    float2 acc;
    {   // self loop + bias
        const unsigned u = h32[(size_t)i * 64 + lane];
        const float2 bv = reinterpret_cast<const float2*>(b)[lane];
        const float w = di * di;
        acc.x = w * bf_lo(u) + bv.x;
        acc.y = w * bf_hi(u) + bv.y;
    }

    int j = beg;
    for (; j + 1 < end; j += 2) {  // 2-deep for memory-level parallelism
        const int s0 = esrc[j];
        const int s1 = esrc[j + 1];
        const float w0 = dis[s0] * di;
        const float w1 = dis[s1] * di;
        const unsigned u0 = h32[(size_t)s0 * 64 + lane];
        const unsigned u1 = h32[(size_t)s1 * 64 + lane];
        acc.x += w0 * bf_lo(u0) + w1 * bf_lo(u1);
        acc.y += w0 * bf_hi(u0) + w1 * bf_hi(u1);
    }
    if (j < end) {
        const int s0 = esrc[j];
        const float w0 = dis[s0] * di;
        const unsigned u0 = h32[(size_t)s0 * 64 + lane];
        acc.x += w0 * bf_lo(u0);
        acc.y += w0 * bf_hi(u0);
    }

    if constexpr (OUT_BF16) {
        const unsigned o = (unsigned)f2bf(acc.x) | ((unsigned)f2bf(acc.y) << 16);
        reinterpret_cast<unsigned*>(outv)[(size_t)i * 64 + lane] = o;
    } else {
        reinterpret_cast<float2*>(outv)[(size_t)i * 64 + lane] = make_float2(acc.x, acc.y);
    }
}

extern "C" void kernel_launch(void* const* d_in, const int* in_sizes, int n_in,
                              void* d_out, int out_size, void* d_ws, size_t ws_size,
                              hipStream_t stream) {
    const float* x  = (const float*)d_in[0];
    const int*   ei = (const int*)d_in[1];   // [2, E]
    const float* W1 = (const float*)d_in[2];
    const float* b1 = (const float*)d_in[3];
    const float* W2 = (const float*)d_in[4];
    const float* b2 = (const float*)d_in[5];
    float* out = (float*)d_out;

    const int n  = in_sizes[0] / D;
    const int nE = in_sizes[1] / 2;
    const int* src = ei;
    const int* dst = ei + nE;

    char* ws = (char*)d_ws;
    float*          dis    = (float*)(ws);                  // n f32
    int*            counts = (int*)(ws + (1ull  << 19));    // n i32
    int*            starts = (int*)(ws + (2ull  << 19));    // n+1 i32
    int*            cursor = (int*)(ws + (3ull  << 19));    // n i32
    int*            esrc   = (int*)(ws + (4ull  << 19));    // nE i32 (~2.4M)
    int*            bsum   = (int*)(ws + (6ull  << 20));    // <=128 i32
    unsigned short* h_bf   = (unsigned short*)(ws + (8ull  << 20));  // n*128 bf16 (~24.4M)
    unsigned short* agg_bf = (unsigned short*)(ws + (40ull << 20));  // n*128 bf16

    const int B = 256;
    const int gn = (n + B - 1) / B;
    const int ge = (nE + B - 1) / B;
    const int nB = (n + 1023) / 1024;  // <=128 for n<=131072

    // CSR by dst (counts also yields degrees: deg = counts + 1 self-loop)
    k_zero1<<<gn, B, 0, stream>>>(counts, n);
    k_hist<<<ge, B, 0, stream>>>(dst, counts, nE);
    k_scan_part<<<nB, B, 0, stream>>>(counts, bsum, dis, n);
    k_scan_final<<<nB, B, 0, stream>>>(counts, bsum, starts, cursor, n, nB);
    k_scatter<<<ge, B, 0, stream>>>(src, dst, cursor, esrc, nE);

    const int nst = (n + 63) / 64;
    const int gemm_blocks = 512;  // 2 blocks/CU, grid-stride over supertiles
    const int agg_grid = (n + 3) / 4;

    // ---- layer 1 ----
    k_gemm_mfma<false, false><<<gemm_blocks, B, 0, stream>>>(x, W1, h_bf, n, nst);
    k_gather_agg<true><<<agg_grid, B, 0, stream>>>(h_bf, starts, esrc, dis, b1, agg_bf, n);

    // ---- layer 2 (ReLU fused into bf16 staging; h_bf reused for h2) ----
    k_gemm_mfma<true, true><<<gemm_blocks, B, 0, stream>>>(agg_bf, W2, h_bf, n, nst);
    k_gather_agg<false><<<agg_grid, B, 0, stream>>>(h_bf, starts, esrc, dis, b2, out, n);
}

// Round 6
// 193.913 us; speedup vs baseline: 4.2793x; 1.0700x over previous
//
#include <hip/hip_runtime.h>

#define D 128

typedef __attribute__((ext_vector_type(8))) short bf16x8;
typedef __attribute__((ext_vector_type(4))) float f32x4;
typedef __attribute__((ext_vector_type(4))) unsigned u32x4;

__device__ inline unsigned short f2bf(float f) {  // RNE fp32->bf16
    unsigned u = __builtin_bit_cast(unsigned, f);
    u += 0x7FFFu + ((u >> 16) & 1u);
    return (unsigned short)(u >> 16);
}
__device__ inline float bf_lo(unsigned u) { return __builtin_bit_cast(float, u << 16); }
__device__ inline float bf_hi(unsigned u) { return __builtin_bit_cast(float, u & 0xFFFF0000u); }

// ---------------- CSR build (by dst) ----------------
__global__ void k_zero1(int* __restrict__ a, int n) {
    int i = blockIdx.x * blockDim.x + threadIdx.x;
    if (i < n) a[i] = 0;
}

__global__ void k_hist(const int* __restrict__ dst, int* __restrict__ counts, int nE) {
    int e4 = (blockIdx.x * blockDim.x + threadIdx.x) * 4;
    if (e4 + 4 <= nE) {
        const int4 d = *reinterpret_cast<const int4*>(dst + e4);
        atomicAdd(&counts[d.x], 1);
        atomicAdd(&counts[d.y], 1);
        atomicAdd(&counts[d.z], 1);
        atomicAdd(&counts[d.w], 1);
    } else {
        for (int e = e4; e < nE; ++e) atomicAdd(&counts[dst[e]], 1);
    }
}

// Pass 1: per-block (1024-element tile) sums; fused dis = rsqrt(counts+1).
__global__ __launch_bounds__(256) void k_scan_part(const int* __restrict__ counts,
                                                   int* __restrict__ bsum,
                                                   float* __restrict__ dis, int n) {
    const int t = threadIdx.x;
    const int base = blockIdx.x * 1024 + t * 4;
    int4 c = make_int4(0, 0, 0, 0);
    if (base + 4 <= n) {
        c = *reinterpret_cast<const int4*>(counts + base);
        float4 dv;
        dv.x = rsqrtf((float)(c.x + 1));
        dv.y = rsqrtf((float)(c.y + 1));
        dv.z = rsqrtf((float)(c.z + 1));
        dv.w = rsqrtf((float)(c.w + 1));
        *reinterpret_cast<float4*>(dis + base) = dv;
    } else if (base < n) {
        int cc[4] = {0, 0, 0, 0};
        for (int k = 0; k < 4; ++k)
            if (base + k < n) {
                cc[k] = counts[base + k];
                dis[base + k] = rsqrtf((float)(cc[k] + 1));
            }
        c.x = cc[0]; c.y = cc[1]; c.z = cc[2]; c.w = cc[3];
    }
    __shared__ int red[256];
    red[t] = c.x + c.y + c.z + c.w;
    __syncthreads();
    for (int off = 128; off > 0; off >>= 1) {
        if (t < off) red[t] += red[t + off];
        __syncthreads();
    }
    if (t == 0) bsum[blockIdx.x] = red[0];
}

// Pass 2: scan block sums in LDS, local-scan tile, write starts AND cursor copy.
__global__ __launch_bounds__(256) void k_scan_final(const int* __restrict__ counts,
                                                    const int* __restrict__ bsum,
                                                    int* __restrict__ starts,
                                                    int* __restrict__ cursor, int n, int nB) {
    __shared__ int sb[128];
    __shared__ int ts[256];
    const int t = threadIdx.x;
    const int b = blockIdx.x;

    if (t < 128) sb[t] = (t < nB) ? bsum[t] : 0;
    __syncthreads();
    for (int off = 1; off < 128; off <<= 1) {
        int add = (t < 128 && t >= off) ? sb[t - off] : 0;
        __syncthreads();
        if (t < 128) sb[t] += add;
        __syncthreads();
    }
    const int block_off = (b > 0) ? sb[b - 1] : 0;

    const int base = b * 1024 + t * 4;
    int4 c = make_int4(0, 0, 0, 0);
    if (base + 4 <= n) {
        c = *reinterpret_cast<const int4*>(counts + base);
    } else if (base < n) {
        if (base + 0 < n) c.x = counts[base + 0];
        if (base + 1 < n) c.y = counts[base + 1];
        if (base + 2 < n) c.z = counts[base + 2];
    }
    const int s = c.x + c.y + c.z + c.w;
    ts[t] = s;
    __syncthreads();
    for (int off = 1; off < 256; off <<= 1) {
        int add = (t >= off) ? ts[t - off] : 0;
        __syncthreads();
        ts[t] += add;
        __syncthreads();
    }
    int excl = block_off + ts[t] - s;

    int4 w;
    w.x = excl;
    w.y = w.x + c.x;
    w.z = w.y + c.y;
    w.w = w.z + c.z;
    if (base + 4 <= n) {
        *reinterpret_cast<int4*>(starts + base) = w;
        *reinterpret_cast<int4*>(cursor + base) = w;
    } else if (base < n) {
        if (base + 0 < n) { starts[base + 0] = w.x; cursor[base + 0] = w.x; }
        if (base + 1 < n) { starts[base + 1] = w.y; cursor[base + 1] = w.y; }
        if (base + 2 < n) { starts[base + 2] = w.z; cursor[base + 2] = w.z; }
    }
    if (b == 0 && t == 0) starts[n] = sb[nB - 1];  // = nE
}

__global__ void k_scatter(const int* __restrict__ src, const int* __restrict__ dst,
                          int* __restrict__ cursor, int* __restrict__ esrc, int nE) {
    int e4 = (blockIdx.x * blockDim.x + threadIdx.x) * 4;
    if (e4 + 4 <= nE) {
        const int4 s = *reinterpret_cast<const int4*>(src + e4);
        const int4 d = *reinterpret_cast<const int4*>(dst + e4);
        esrc[atomicAdd(&cursor[d.x], 1)] = s.x;
        esrc[atomicAdd(&cursor[d.y], 1)] = s.y;
        esrc[atomicAdd(&cursor[d.z], 1)] = s.z;
        esrc[atomicAdd(&cursor[d.w], 1)] = s.w;
    } else {
        for (int e = e4; e < nE; ++e)
            esrc[atomicAdd(&cursor[dst[e]], 1)] = src[e];
    }
}

// ---------------- MFMA GEMM: hs_bf16[n,128] = dis .* ((relu?)(X) @ W) ----------------
// W held per-wave as 32 bf16 B-fragments in regs. A staged per 64-row supertile
// through XOR-swizzled LDS. Epilogue pre-scales rows by dis[row] (folds the src-side
// normalization so the gather needs no per-edge dis load).
template <bool IN_BF16, bool RELU>
__global__ __launch_bounds__(256, 2) void k_gemm_mfma(const void* __restrict__ Xv,
                                                      const float* __restrict__ W,
                                                      const float* __restrict__ dis,
                                                      unsigned short* __restrict__ outbf,
                                                      int n, int nst) {
    __shared__ __align__(16) unsigned short At[64 * 128];  // 16KB, swizzled
    const int tid = threadIdx.x;
    const int lane = tid & 63;
    const int wv = tid >> 6;
    const int col16 = lane & 15;
    const int kgrp = lane >> 4;

    // ---- W -> 32 register B-fragments ----
    bf16x8 bw[8][4];
#pragma unroll
    for (int ct = 0; ct < 8; ++ct)
#pragma unroll
        for (int kk = 0; kk < 4; ++kk)
#pragma unroll
            for (int e = 0; e < 8; ++e) {
                const int k = kk * 32 + kgrp * 8 + e;
                bw[ct][kk][e] = (short)f2bf(W[k * D + ct * 16 + col16]);
            }

    for (int st = blockIdx.x; st < nst; st += gridDim.x) {
        __syncthreads();  // prior compute done reading At
        // ---- stage 64x128 supertile to LDS (bf16, elem-swizzle col ^ ((row&7)<<3)) ----
#pragma unroll
        for (int c = 0; c < 4; ++c) {
            const int idx = c * 2048 + tid * 8;  // 8 consecutive elems per thread
            const int row = idx >> 7;
            const int col = idx & 127;
            int grow = st * 64 + row;
            if (grow >= n) grow = n - 1;  // clamp reads; stores masked
            bf16x8 d;
            if constexpr (IN_BF16) {
                d = *reinterpret_cast<const bf16x8*>(
                        (const unsigned short*)Xv + (size_t)grow * D + col);
                if (RELU) {
#pragma unroll
                    for (int e = 0; e < 8; ++e)
                        d[e] = (short)((d[e] & (short)0x8000) ? 0 : d[e]);
                }
            } else {
                const float4* p = reinterpret_cast<const float4*>(
                        (const float*)Xv + (size_t)grow * D + col);
                const float4 f0 = p[0], f1 = p[1];
                float v[8] = {f0.x, f0.y, f0.z, f0.w, f1.x, f1.y, f1.z, f1.w};
#pragma unroll
                for (int e = 0; e < 8; ++e) {
                    float f = v[e];
                    if (RELU) f = fmaxf(f, 0.0f);
                    d[e] = (short)f2bf(f);
                }
            }
            const int waddr = row * 128 + (col ^ ((row & 7) << 3));
            *reinterpret_cast<bf16x8*>(&At[waddr]) = d;
        }
        __syncthreads();

        // ---- compute: wave wv handles rows wv*16..wv*16+15 ----
        bf16x8 a[4];
#pragma unroll
        for (int kk = 0; kk < 4; ++kk) {
            const int raddr = (wv * 16 + col16) * 128 +
                              ((kk * 32 + kgrp * 8) ^ ((col16 & 7) << 3));
            a[kk] = *reinterpret_cast<const bf16x8*>(&At[raddr]);
        }

        f32x4 acc[8];
#pragma unroll
        for (int ct = 0; ct < 8; ++ct) acc[ct] = (f32x4){0.f, 0.f, 0.f, 0.f};
#pragma unroll
        for (int kk = 0; kk < 4; ++kk)
#pragma unroll
            for (int ct = 0; ct < 8; ++ct)
                acc[ct] = __builtin_amdgcn_mfma_f32_16x16x32_bf16(a[kk], bw[ct][kk], acc[ct], 0, 0, 0);

        const int rowbase = st * 64 + wv * 16;
        float dr[4];
#pragma unroll
        for (int r = 0; r < 4; ++r) {
            const int row = rowbase + kgrp * 4 + r;
            dr[r] = (row < n) ? dis[row] : 0.0f;
        }
#pragma unroll
        for (int ct = 0; ct < 8; ++ct)
#pragma unroll
            for (int r = 0; r < 4; ++r) {
                const int row = rowbase + kgrp * 4 + r;
                if (row < n)
                    outbf[(size_t)row * D + ct * 16 + col16] = f2bf(dr[r] * acc[ct][r]);
            }
    }
}

// ---------------- gather-aggregate (pre-scaled bf16 hs, fp32 accumulate) ----------------
// 4 nodes per wave (16 lanes/node, 16B per lane):
//   out[i] = dis[i] * ( hs[i] + sum_{j in in(i)} hs[src_j] ) + b
template <bool OUT_BF16>
__global__ __launch_bounds__(256) void k_gather_agg(const unsigned short* __restrict__ hs,
                                                    const int* __restrict__ starts,
                                                    const int* __restrict__ esrc,
                                                    const float* __restrict__ dis,
                                                    const float* __restrict__ b,
                                                    void* __restrict__ outv, int n) {
    const int lane = threadIdx.x & 63;
    const int wv = threadIdx.x >> 6;
    const int grp = lane >> 4;   // 0..3 node within wave
    const int sub = lane & 15;   // 0..15 lane within node
    const int i = (blockIdx.x * 4 + wv) * 4 + grp;
    const bool active = (i < n);
    const int ic = active ? i : (n - 1);

    const float di = dis[ic];
    const int beg = starts[ic];
    const int end = starts[ic + 1];

    auto row16 = [&](int s) -> u32x4 {
        return *reinterpret_cast<const u32x4*>(hs + (size_t)s * D + sub * 8);
    };

    float acc[8];
    {   // self-loop row
        const u32x4 u = row16(ic);
#pragma unroll
        for (int e = 0; e < 4; ++e) {
            acc[2 * e] = bf_lo(u[e]);
            acc[2 * e + 1] = bf_hi(u[e]);
        }
    }

#define ACCUM(u)                              \
    _Pragma("unroll") for (int e = 0; e < 4; ++e) { \
        acc[2 * e] += bf_lo((u)[e]);          \
        acc[2 * e + 1] += bf_hi((u)[e]);      \
    }

    int j = beg;
    while (j < end) {
        const int cnt = min(end - j, 16);
        const int myedge = (sub < cnt) ? esrc[j + sub] : 0;  // coalesced chunk
        int k = 0;
        for (; k + 4 <= cnt; k += 4) {
            const int s0 = __shfl(myedge, (grp << 4) | (k + 0));
            const int s1 = __shfl(myedge, (grp << 4) | (k + 1));
            const int s2 = __shfl(myedge, (grp << 4) | (k + 2));
            const int s3 = __shfl(myedge, (grp << 4) | (k + 3));
            const u32x4 u0 = row16(s0);
            const u32x4 u1 = row16(s1);
            const u32x4 u2 = row16(s2);
            const u32x4 u3 = row16(s3);
            ACCUM(u0) ACCUM(u1) ACCUM(u2) ACCUM(u3)
        }
        for (; k < cnt; ++k) {
            const int s0 = __shfl(myedge, (grp << 4) | k);
            const u32x4 u0 = row16(s0);
            ACCUM(u0)
        }
        j += 16;
    }
#undef ACCUM

    if (!active) return;

    const float4 bv0 = reinterpret_cast<const float4*>(b)[sub * 2 + 0];
    const float4 bv1 = reinterpret_cast<const float4*>(b)[sub * 2 + 1];
    float o[8];
    o[0] = di * acc[0] + bv0.x; o[1] = di * acc[1] + bv0.y;
    o[2] = di * acc[2] + bv0.z; o[3] = di * acc[3] + bv0.w;
    o[4] = di * acc[4] + bv1.x; o[5] = di * acc[5] + bv1.y;
    o[6] = di * acc[6] + bv1.z; o[7] = di * acc[7] + bv1.w;

    if constexpr (OUT_BF16) {
        u32x4 w;
#pragma unroll
        for (int e = 0; e < 4; ++e)
            w[e] = (unsigned)f2bf(o[2 * e]) | ((unsigned)f2bf(o[2 * e + 1]) << 16);
        *reinterpret_cast<u32x4*>((unsigned short*)outv + (size_t)i * D + sub * 8) = w;
    } else {
        float4* op = reinterpret_cast<float4*>((float*)outv + (size_t)i * D + sub * 8);
        op[0] = make_float4(o[0], o[1], o[2], o[3]);
        op[1] = make_float4(o[4], o[5], o[6], o[7]);
    }
}

extern "C" void kernel_launch(void* const* d_in, const int* in_sizes, int n_in,
                              void* d_out, int out_size, void* d_ws, size_t ws_size,
                              hipStream_t stream) {
    const float* x  = (const float*)d_in[0];
    const int*   ei = (const int*)d_in[1];   // [2, E]
    const float* W1 = (const float*)d_in[2];
    const float* b1 = (const float*)d_in[3];
    const float* W2 = (const float*)d_in[4];
    const float* b2 = (const float*)d_in[5];
    float* out = (float*)d_out;

    const int n  = in_sizes[0] / D;
    const int nE = in_sizes[1] / 2;
    const int* src = ei;
    const int* dst = ei + nE;

    char* ws = (char*)d_ws;
    float*          dis    = (float*)(ws);                  // n f32
    int*            counts = (int*)(ws + (1ull  << 19));    // n i32
    int*            starts = (int*)(ws + (2ull  << 19));    // n+1 i32
    int*            cursor = (int*)(ws + (3ull  << 19));    // n i32
    int*            esrc   = (int*)(ws + (4ull  << 19));    // nE i32 (~2.4M)
    int*            bsum   = (int*)(ws + (6ull  << 20));    // <=128 i32
    unsigned short* hs_bf  = (unsigned short*)(ws + (8ull  << 20));  // n*128 bf16 (~24.4M)
    unsigned short* agg_bf = (unsigned short*)(ws + (40ull << 20));  // n*128 bf16

    const int B = 256;
    const int gn = (n + B - 1) / B;
    const int ge4 = (nE + B * 4 - 1) / (B * 4);
    const int nB = (n + 1023) / 1024;  // <=128 for n<=131072

    // CSR by dst (counts also yields degrees: deg = counts + 1 self-loop)
    k_zero1<<<gn, B, 0, stream>>>(counts, n);
    k_hist<<<ge4, B, 0, stream>>>(dst, counts, nE);
    k_scan_part<<<nB, B, 0, stream>>>(counts, bsum, dis, n);
    k_scan_final<<<nB, B, 0, stream>>>(counts, bsum, starts, cursor, n, nB);
    k_scatter<<<ge4, B, 0, stream>>>(src, dst, cursor, esrc, nE);

    const int nst = (n + 63) / 64;
    const int gemm_blocks = 512;  // 2 blocks/CU, grid-stride over supertiles
    const int agg_grid = (n + 15) / 16;

    // ---- layer 1 ----
    k_gemm_mfma<false, false><<<gemm_blocks, B, 0, stream>>>(x, W1, dis, hs_bf, n, nst);
    k_gather_agg<true><<<agg_grid, B, 0, stream>>>(hs_bf, starts, esrc, dis, b1, agg_bf, n);

    // ---- layer 2 (ReLU fused into bf16 staging; hs_bf reused) ----
    k_gemm_mfma<true, true><<<gemm_blocks, B, 0, stream>>>(agg_bf, W2, dis, hs_bf, n, nst);
    k_gather_agg<false><<<agg_grid, B, 0, stream>>>(hs_bf, starts, esrc, dis, b2, out, n);
}

// Round 7
// 173.446 us; speedup vs baseline: 4.7842x; 1.1180x over previous
//
#include <hip/hip_runtime.h>

#define D 128

typedef __attribute__((ext_vector_type(8))) short bf16x8;
typedef __attribute__((ext_vector_type(4))) float f32x4;
typedef __attribute__((ext_vector_type(4))) unsigned u32x4;

__device__ inline unsigned short f2bf(float f) {  // RNE fp32->bf16
    unsigned u = __builtin_bit_cast(unsigned, f);
    u += 0x7FFFu + ((u >> 16) & 1u);
    return (unsigned short)(u >> 16);
}
__device__ inline float bf_lo(unsigned u) { return __builtin_bit_cast(float, u << 16); }
__device__ inline float bf_hi(unsigned u) { return __builtin_bit_cast(float, u & 0xFFFF0000u); }

// ---------------- CSR build (by dst) ----------------
__global__ void k_zero1(int* __restrict__ a, int n) {
    int i = blockIdx.x * blockDim.x + threadIdx.x;
    if (i < n) a[i] = 0;
}

// Histogram that also records each edge's rank within its dst segment
// (atomicAdd return value). Makes the scatter pass atomic-free.
__global__ void k_hist_rank(const int* __restrict__ dst, int* __restrict__ counts,
                            int* __restrict__ rank, int nE) {
    int e4 = (blockIdx.x * blockDim.x + threadIdx.x) * 4;
    if (e4 + 4 <= nE) {
        const int4 d = *reinterpret_cast<const int4*>(dst + e4);
        int4 r;
        r.x = atomicAdd(&counts[d.x], 1);
        r.y = atomicAdd(&counts[d.y], 1);
        r.z = atomicAdd(&counts[d.z], 1);
        r.w = atomicAdd(&counts[d.w], 1);
        *reinterpret_cast<int4*>(rank + e4) = r;
    } else {
        for (int e = e4; e < nE; ++e) rank[e] = atomicAdd(&counts[dst[e]], 1);
    }
}

// Pass 1: per-block (1024-element tile) sums; fused dis = rsqrt(counts+1).
__global__ __launch_bounds__(256) void k_scan_part(const int* __restrict__ counts,
                                                   int* __restrict__ bsum,
                                                   float* __restrict__ dis, int n) {
    const int t = threadIdx.x;
    const int base = blockIdx.x * 1024 + t * 4;
    int4 c = make_int4(0, 0, 0, 0);
    if (base + 4 <= n) {
        c = *reinterpret_cast<const int4*>(counts + base);
        float4 dv;
        dv.x = rsqrtf((float)(c.x + 1));
        dv.y = rsqrtf((float)(c.y + 1));
        dv.z = rsqrtf((float)(c.z + 1));
        dv.w = rsqrtf((float)(c.w + 1));
        *reinterpret_cast<float4*>(dis + base) = dv;
    } else if (base < n) {
        int cc[4] = {0, 0, 0, 0};
        for (int k = 0; k < 4; ++k)
            if (base + k < n) {
                cc[k] = counts[base + k];
                dis[base + k] = rsqrtf((float)(cc[k] + 1));
            }
        c.x = cc[0]; c.y = cc[1]; c.z = cc[2]; c.w = cc[3];
    }
    __shared__ int red[256];
    red[t] = c.x + c.y + c.z + c.w;
    __syncthreads();
    for (int off = 128; off > 0; off >>= 1) {
        if (t < off) red[t] += red[t + off];
        __syncthreads();
    }
    if (t == 0) bsum[blockIdx.x] = red[0];
}

// Pass 2: scan block sums in LDS, local-scan tile, write starts.
__global__ __launch_bounds__(256) void k_scan_final(const int* __restrict__ counts,
                                                    const int* __restrict__ bsum,
                                                    int* __restrict__ starts, int n, int nB) {
    __shared__ int sb[128];
    __shared__ int ts[256];
    const int t = threadIdx.x;
    const int b = blockIdx.x;

    if (t < 128) sb[t] = (t < nB) ? bsum[t] : 0;
    __syncthreads();
    for (int off = 1; off < 128; off <<= 1) {
        int add = (t < 128 && t >= off) ? sb[t - off] : 0;
        __syncthreads();
        if (t < 128) sb[t] += add;
        __syncthreads();
    }
    const int block_off = (b > 0) ? sb[b - 1] : 0;

    const int base = b * 1024 + t * 4;
    int4 c = make_int4(0, 0, 0, 0);
    if (base + 4 <= n) {
        c = *reinterpret_cast<const int4*>(counts + base);
    } else if (base < n) {
        if (base + 0 < n) c.x = counts[base + 0];
        if (base + 1 < n) c.y = counts[base + 1];
        if (base + 2 < n) c.z = counts[base + 2];
    }
    const int s = c.x + c.y + c.z + c.w;
    ts[t] = s;
    __syncthreads();
    for (int off = 1; off < 256; off <<= 1) {
        int add = (t >= off) ? ts[t - off] : 0;
        __syncthreads();
        ts[t] += add;
        __syncthreads();
    }
    int excl = block_off + ts[t] - s;

    int4 w;
    w.x = excl;
    w.y = w.x + c.x;
    w.z = w.y + c.y;
    w.w = w.z + c.z;
    if (base + 4 <= n) {
        *reinterpret_cast<int4*>(starts + base) = w;
    } else if (base < n) {
        if (base + 0 < n) starts[base + 0] = w.x;
        if (base + 1 < n) starts[base + 1] = w.y;
        if (base + 2 < n) starts[base + 2] = w.z;
    }
    if (b == 0 && t == 0) starts[n] = sb[nB - 1];  // = nE
}

// Atomic-free scatter: position = starts[dst] + precomputed rank.
__global__ void k_scatter_nr(const int* __restrict__ src, const int* __restrict__ dst,
                             const int* __restrict__ rank, const int* __restrict__ starts,
                             int* __restrict__ esrc, int nE) {
    int e4 = (blockIdx.x * blockDim.x + threadIdx.x) * 4;
    if (e4 + 4 <= nE) {
        const int4 s = *reinterpret_cast<const int4*>(src + e4);
        const int4 d = *reinterpret_cast<const int4*>(dst + e4);
        const int4 r = *reinterpret_cast<const int4*>(rank + e4);
        esrc[starts[d.x] + r.x] = s.x;
        esrc[starts[d.y] + r.y] = s.y;
        esrc[starts[d.z] + r.z] = s.z;
        esrc[starts[d.w] + r.w] = s.w;
    } else {
        for (int e = e4; e < nE; ++e)
            esrc[starts[dst[e]] + rank[e]] = src[e];
    }
}

// ---------------- MFMA GEMM: hs_bf16[n,128] = dis .* ((relu?)(X) @ W) ----------------
// W per-wave as 32 bf16 B-fragments in regs. Double-buffered LDS supertile with
// register prefetch (T14: issue next tile's global loads before the barrier, so
// HBM latency hides under MFMA+stores). One barrier per iteration.
template <bool IN_BF16, bool RELU>
__global__ __launch_bounds__(256, 2) void k_gemm_mfma(const void* __restrict__ Xv,
                                                      const float* __restrict__ W,
                                                      const float* __restrict__ dis,
                                                      unsigned short* __restrict__ outbf,
                                                      int n, int nst) {
    __shared__ __align__(16) unsigned short At[2][64 * 128];  // 2 x 16KB, swizzled
    const int tid = threadIdx.x;
    const int lane = tid & 63;
    const int wv = tid >> 6;
    const int col16 = lane & 15;
    const int kgrp = lane >> 4;

    // ---- W -> 32 register B-fragments ----
    bf16x8 bw[8][4];
#pragma unroll
    for (int ct = 0; ct < 8; ++ct)
#pragma unroll
        for (int kk = 0; kk < 4; ++kk)
#pragma unroll
            for (int e = 0; e < 8; ++e) {
                const int k = kk * 32 + kgrp * 8 + e;
                bw[ct][kk][e] = (short)f2bf(W[k * D + ct * 16 + col16]);
            }

    int st = blockIdx.x;
    if (st >= nst) return;  // uniform per block

    float4 pf[8];   // fp32 prefetch regs
    bf16x8 pb[4];   // bf16 prefetch regs

    auto LOAD = [&](int t) {
#pragma unroll
        for (int c = 0; c < 4; ++c) {
            const int idx = c * 2048 + tid * 8;
            const int row = idx >> 7;
            const int col = idx & 127;
            int grow = t * 64 + row;
            if (grow >= n) grow = n - 1;  // clamp reads; stores masked
            if constexpr (IN_BF16) {
                pb[c] = *reinterpret_cast<const bf16x8*>(
                        (const unsigned short*)Xv + (size_t)grow * D + col);
            } else {
                const float4* p = reinterpret_cast<const float4*>(
                        (const float*)Xv + (size_t)grow * D + col);
                pf[2 * c] = p[0];
                pf[2 * c + 1] = p[1];
            }
        }
    };

    LOAD(st);
    int buf = 0;
    for (;;) {
        // ---- convert + ds_write to At[buf] (elem-swizzle col ^ ((row&7)<<3)) ----
#pragma unroll
        for (int c = 0; c < 4; ++c) {
            const int idx = c * 2048 + tid * 8;
            const int row = idx >> 7;
            const int col = idx & 127;
            bf16x8 d;
            if constexpr (IN_BF16) {
                d = pb[c];
                if (RELU) {
#pragma unroll
                    for (int e = 0; e < 8; ++e)
                        d[e] = (short)((d[e] & (short)0x8000) ? 0 : d[e]);
                }
            } else {
                const float4 f0 = pf[2 * c], f1 = pf[2 * c + 1];
                float v[8] = {f0.x, f0.y, f0.z, f0.w, f1.x, f1.y, f1.z, f1.w};
#pragma unroll
                for (int e = 0; e < 8; ++e) {
                    float f = v[e];
                    if (RELU) f = fmaxf(f, 0.0f);
                    d[e] = (short)f2bf(f);
                }
            }
            const int waddr = row * 128 + (col ^ ((row & 7) << 3));
            *reinterpret_cast<bf16x8*>(&At[buf][waddr]) = d;
        }

        const int next = st + gridDim.x;
        if (next < nst) LOAD(next);  // issue early; consumed next iteration

        __syncthreads();

        // ---- compute: wave wv handles rows wv*16..wv*16+15 ----
        bf16x8 a[4];
#pragma unroll
        for (int kk = 0; kk < 4; ++kk) {
            const int raddr = (wv * 16 + col16) * 128 +
                              ((kk * 32 + kgrp * 8) ^ ((col16 & 7) << 3));
            a[kk] = *reinterpret_cast<const bf16x8*>(&At[buf][raddr]);
        }

        f32x4 acc[8];
#pragma unroll
        for (int ct = 0; ct < 8; ++ct) acc[ct] = (f32x4){0.f, 0.f, 0.f, 0.f};
#pragma unroll
        for (int kk = 0; kk < 4; ++kk)
#pragma unroll
            for (int ct = 0; ct < 8; ++ct)
                acc[ct] = __builtin_amdgcn_mfma_f32_16x16x32_bf16(a[kk], bw[ct][kk], acc[ct], 0, 0, 0);

        const int rowbase = st * 64 + wv * 16;
        float dr[4];
#pragma unroll
        for (int r = 0; r < 4; ++r) {
            const int row = rowbase + kgrp * 4 + r;
            dr[r] = (row < n) ? dis[row] : 0.0f;
        }
#pragma unroll
        for (int ct = 0; ct < 8; ++ct)
#pragma unroll
            for (int r = 0; r < 4; ++r) {
                const int row = rowbase + kgrp * 4 + r;
                if (row < n)
                    outbf[(size_t)row * D + ct * 16 + col16] = f2bf(dr[r] * acc[ct][r]);
            }

        if (next >= nst) break;
        st = next;
        buf ^= 1;
    }
}

// ---------------- gather-aggregate (pre-scaled bf16 hs, fp32 accumulate) ----------------
// 4 nodes per wave (16 lanes/node, 16B per lane):
//   out[i] = dis[i] * ( hs[i] + sum_{j in in(i)} hs[src_j] ) + b
template <bool OUT_BF16>
__global__ __launch_bounds__(256) void k_gather_agg(const unsigned short* __restrict__ hs,
                                                    const int* __restrict__ starts,
                                                    const int* __restrict__ esrc,
                                                    const float* __restrict__ dis,
                                                    const float* __restrict__ b,
                                                    void* __restrict__ outv, int n) {
    const int lane = threadIdx.x & 63;
    const int wv = threadIdx.x >> 6;
    const int grp = lane >> 4;   // 0..3 node within wave
    const int sub = lane & 15;   // 0..15 lane within node
    const int i = (blockIdx.x * 4 + wv) * 4 + grp;
    const bool active = (i < n);
    const int ic = active ? i : (n - 1);

    const float di = dis[ic];
    const int beg = starts[ic];
    const int end = starts[ic + 1];

    auto row16 = [&](int s) -> u32x4 {
        return *reinterpret_cast<const u32x4*>(hs + (size_t)s * D + sub * 8);
    };

    float acc[8];
    {   // self-loop row
        const u32x4 u = row16(ic);
#pragma unroll
        for (int e = 0; e < 4; ++e) {
            acc[2 * e] = bf_lo(u[e]);
            acc[2 * e + 1] = bf_hi(u[e]);
        }
    }

#define ACCUM(u)                              \
    _Pragma("unroll") for (int e = 0; e < 4; ++e) { \
        acc[2 * e] += bf_lo((u)[e]);          \
        acc[2 * e + 1] += bf_hi((u)[e]);      \
    }

    int j = beg;
    while (j < end) {
        const int cnt = min(end - j, 16);
        const int myedge = (sub < cnt) ? esrc[j + sub] : 0;  // coalesced chunk
        int k = 0;
        for (; k + 4 <= cnt; k += 4) {
            const int s0 = __shfl(myedge, (grp << 4) | (k + 0));
            const int s1 = __shfl(myedge, (grp << 4) | (k + 1));
            const int s2 = __shfl(myedge, (grp << 4) | (k + 2));
            const int s3 = __shfl(myedge, (grp << 4) | (k + 3));
            const u32x4 u0 = row16(s0);
            const u32x4 u1 = row16(s1);
            const u32x4 u2 = row16(s2);
            const u32x4 u3 = row16(s3);
            ACCUM(u0) ACCUM(u1) ACCUM(u2) ACCUM(u3)
        }
        for (; k < cnt; ++k) {
            const int s0 = __shfl(myedge, (grp << 4) | k);
            const u32x4 u0 = row16(s0);
            ACCUM(u0)
        }
        j += 16;
    }
#undef ACCUM

    if (!active) return;

    const float4 bv0 = reinterpret_cast<const float4*>(b)[sub * 2 + 0];
    const float4 bv1 = reinterpret_cast<const float4*>(b)[sub * 2 + 1];
    float o[8];
    o[0] = di * acc[0] + bv0.x; o[1] = di * acc[1] + bv0.y;
    o[2] = di * acc[2] + bv0.z; o[3] = di * acc[3] + bv0.w;
    o[4] = di * acc[4] + bv1.x; o[5] = di * acc[5] + bv1.y;
    o[6] = di * acc[6] + bv1.z; o[7] = di * acc[7] + bv1.w;

    if constexpr (OUT_BF16) {
        u32x4 w;
#pragma unroll
        for (int e = 0; e < 4; ++e)
            w[e] = (unsigned)f2bf(o[2 * e]) | ((unsigned)f2bf(o[2 * e + 1]) << 16);
        *reinterpret_cast<u32x4*>((unsigned short*)outv + (size_t)i * D + sub * 8) = w;
    } else {
        float4* op = reinterpret_cast<float4*>((float*)outv + (size_t)i * D + sub * 8);
        op[0] = make_float4(o[0], o[1], o[2], o[3]);
        op[1] = make_float4(o[4], o[5], o[6], o[7]);
    }
}

extern "C" void kernel_launch(void* const* d_in, const int* in_sizes, int n_in,
                              void* d_out, int out_size, void* d_ws, size_t ws_size,
                              hipStream_t stream) {
    const float* x  = (const float*)d_in[0];
    const int*   ei = (const int*)d_in[1];   // [2, E]
    const float* W1 = (const float*)d_in[2];
    const float* b1 = (const float*)d_in[3];
    const float* W2 = (const float*)d_in[4];
    const float* b2 = (const float*)d_in[5];
    float* out = (float*)d_out;

    const int n  = in_sizes[0] / D;
    const int nE = in_sizes[1] / 2;
    const int* src = ei;
    const int* dst = ei + nE;

    char* ws = (char*)d_ws;
    float*          dis    = (float*)(ws);                  // n f32
    int*            counts = (int*)(ws + (1ull  << 19));    // n i32
    int*            starts = (int*)(ws + (2ull  << 19));    // n+1 i32
    int*            esrc   = (int*)(ws + (4ull  << 19));    // nE i32 (2..4.4M)
    int*            bsum   = (int*)(ws + (6ull  << 20));    // <=128 i32
    unsigned short* hs_bf  = (unsigned short*)(ws + (8ull  << 20));  // n*128 bf16 (8..33.6M)
    int*            rank   = (int*)(ws + (34ull << 20));    // nE i32 (34..36.4M)
    unsigned short* agg_bf = (unsigned short*)(ws + (40ull << 20));  // n*128 bf16

    const int B = 256;
    const int gn = (n + B - 1) / B;
    const int ge4 = (nE + B * 4 - 1) / (B * 4);
    const int nB = (n + 1023) / 1024;  // <=128 for n<=131072

    // CSR by dst (counts also yields degrees: deg = counts + 1 self-loop)
    k_zero1<<<gn, B, 0, stream>>>(counts, n);
    k_hist_rank<<<ge4, B, 0, stream>>>(dst, counts, rank, nE);
    k_scan_part<<<nB, B, 0, stream>>>(counts, bsum, dis, n);
    k_scan_final<<<nB, B, 0, stream>>>(counts, bsum, starts, n, nB);
    k_scatter_nr<<<ge4, B, 0, stream>>>(src, dst, rank, starts, esrc, nE);

    const int nst = (n + 63) / 64;
    const int gemm_blocks = 512;  // 2 blocks/CU, grid-stride with prefetch
    const int agg_grid = (n + 15) / 16;

    // ---- layer 1 ----
    k_gemm_mfma<false, false><<<gemm_blocks, B, 0, stream>>>(x, W1, dis, hs_bf, n, nst);
    k_gather_agg<true><<<agg_grid, B, 0, stream>>>(hs_bf, starts, esrc, dis, b1, agg_bf, n);

    // ---- layer 2 (ReLU fused into bf16 staging; hs_bf reused) ----
    k_gemm_mfma<true, true><<<gemm_blocks, B, 0, stream>>>(agg_bf, W2, dis, hs_bf, n, nst);
    k_gather_agg<false><<<agg_grid, B, 0, stream>>>(hs_bf, starts, esrc, dis, b2, out, n);
}

// Round 8
// 172.441 us; speedup vs baseline: 4.8121x; 1.0058x over previous
//
#include <hip/hip_runtime.h>

#define D 128

typedef __attribute__((ext_vector_type(8))) short bf16x8;
typedef __attribute__((ext_vector_type(4))) float f32x4;
typedef __attribute__((ext_vector_type(4))) unsigned u32x4;

__device__ inline unsigned short f2bf(float f) {  // RNE fp32->bf16
    unsigned u = __builtin_bit_cast(unsigned, f);
    u += 0x7FFFu + ((u >> 16) & 1u);
    return (unsigned short)(u >> 16);
}
__device__ inline float bf_lo(unsigned u) { return __builtin_bit_cast(float, u << 16); }
__device__ inline float bf_hi(unsigned u) { return __builtin_bit_cast(float, u & 0xFFFF0000u); }

// ---------------- CSR build (by dst) ----------------
__global__ void k_zero1(int* __restrict__ a, int n) {
    int i = blockIdx.x * blockDim.x + threadIdx.x;
    if (i < n) a[i] = 0;
}

// Histogram that also records each edge's rank within its dst segment
// (atomicAdd return value). Makes the scatter pass atomic-free.
__global__ void k_hist_rank(const int* __restrict__ dst, int* __restrict__ counts,
                            int* __restrict__ rank, int nE) {
    int e4 = (blockIdx.x * blockDim.x + threadIdx.x) * 4;
    if (e4 + 4 <= nE) {
        const int4 d = *reinterpret_cast<const int4*>(dst + e4);
        int4 r;
        r.x = atomicAdd(&counts[d.x], 1);
        r.y = atomicAdd(&counts[d.y], 1);
        r.z = atomicAdd(&counts[d.z], 1);
        r.w = atomicAdd(&counts[d.w], 1);
        *reinterpret_cast<int4*>(rank + e4) = r;
    } else {
        for (int e = e4; e < nE; ++e) rank[e] = atomicAdd(&counts[dst[e]], 1);
    }
}

// Pass 1: per-block (1024-element tile) sums; fused dis = rsqrt(counts+1).
__global__ __launch_bounds__(256) void k_scan_part(const int* __restrict__ counts,
                                                   int* __restrict__ bsum,
                                                   float* __restrict__ dis, int n) {
    const int t = threadIdx.x;
    const int base = blockIdx.x * 1024 + t * 4;
    int4 c = make_int4(0, 0, 0, 0);
    if (base + 4 <= n) {
        c = *reinterpret_cast<const int4*>(counts + base);
        float4 dv;
        dv.x = rsqrtf((float)(c.x + 1));
        dv.y = rsqrtf((float)(c.y + 1));
        dv.z = rsqrtf((float)(c.z + 1));
        dv.w = rsqrtf((float)(c.w + 1));
        *reinterpret_cast<float4*>(dis + base) = dv;
    } else if (base < n) {
        int cc[4] = {0, 0, 0, 0};
        for (int k = 0; k < 4; ++k)
            if (base + k < n) {
                cc[k] = counts[base + k];
                dis[base + k] = rsqrtf((float)(cc[k] + 1));
            }
        c.x = cc[0]; c.y = cc[1]; c.z = cc[2]; c.w = cc[3];
    }
    __shared__ int red[256];
    red[t] = c.x + c.y + c.z + c.w;
    __syncthreads();
    for (int off = 128; off > 0; off >>= 1) {
        if (t < off) red[t] += red[t + off];
        __syncthreads();
    }
    if (t == 0) bsum[blockIdx.x] = red[0];
}

// Pass 2: scan block sums in LDS, local-scan tile, write starts.
__global__ __launch_bounds__(256) void k_scan_final(const int* __restrict__ counts,
                                                    const int* __restrict__ bsum,
                                                    int* __restrict__ starts, int n, int nB) {
    __shared__ int sb[128];
    __shared__ int ts[256];
    const int t = threadIdx.x;
    const int b = blockIdx.x;

    if (t < 128) sb[t] = (t < nB) ? bsum[t] : 0;
    __syncthreads();
    for (int off = 1; off < 128; off <<= 1) {
        int add = (t < 128 && t >= off) ? sb[t - off] : 0;
        __syncthreads();
        if (t < 128) sb[t] += add;
        __syncthreads();
    }
    const int block_off = (b > 0) ? sb[b - 1] : 0;

    const int base = b * 1024 + t * 4;
    int4 c = make_int4(0, 0, 0, 0);
    if (base + 4 <= n) {
        c = *reinterpret_cast<const int4*>(counts + base);
    } else if (base < n) {
        if (base + 0 < n) c.x = counts[base + 0];
        if (base + 1 < n) c.y = counts[base + 1];
        if (base + 2 < n) c.z = counts[base + 2];
    }
    const int s = c.x + c.y + c.z + c.w;
    ts[t] = s;
    __syncthreads();
    for (int off = 1; off < 256; off <<= 1) {
        int add = (t >= off) ? ts[t - off] : 0;
        __syncthreads();
        ts[t] += add;
        __syncthreads();
    }
    int excl = block_off + ts[t] - s;

    int4 w;
    w.x = excl;
    w.y = w.x + c.x;
    w.z = w.y + c.y;
    w.w = w.z + c.z;
    if (base + 4 <= n) {
        *reinterpret_cast<int4*>(starts + base) = w;
    } else if (base < n) {
        if (base + 0 < n) starts[base + 0] = w.x;
        if (base + 1 < n) starts[base + 1] = w.y;
        if (base + 2 < n) starts[base + 2] = w.z;
    }
    if (b == 0 && t == 0) starts[n] = sb[nB - 1];  // = nE
}

// Atomic-free scatter: position = starts[dst] + precomputed rank.
__global__ void k_scatter_nr(const int* __restrict__ src, const int* __restrict__ dst,
                             const int* __restrict__ rank, const int* __restrict__ starts,
                             int* __restrict__ esrc, int nE) {
    int e4 = (blockIdx.x * blockDim.x + threadIdx.x) * 4;
    if (e4 + 4 <= nE) {
        const int4 s = *reinterpret_cast<const int4*>(src + e4);
        const int4 d = *reinterpret_cast<const int4*>(dst + e4);
        const int4 r = *reinterpret_cast<const int4*>(rank + e4);
        esrc[starts[d.x] + r.x] = s.x;
        esrc[starts[d.y] + r.y] = s.y;
        esrc[starts[d.z] + r.z] = s.z;
        esrc[starts[d.w] + r.w] = s.w;
    } else {
        for (int e = e4; e < nE; ++e)
            esrc[starts[dst[e]] + rank[e]] = src[e];
    }
}

// ---------------- MFMA GEMM: hs_bf16[n,128] = dis .* ((relu?)(X) @ W) ----------------
// W per-wave as 32 bf16 B-fragments in regs. Double-buffered LDS supertile.
// KEY ORDER (R7): prefetch LOAD(next) is issued AFTER __syncthreads(), because the
// compiler drains vmcnt(0) before every s_barrier — a load issued pre-barrier is
// dead on arrival (R6 lesson). Loads now fly across MFMA+stores+next convert.
template <bool IN_BF16, bool RELU>
__global__ __launch_bounds__(256, 2) void k_gemm_mfma(const void* __restrict__ Xv,
                                                      const float* __restrict__ W,
                                                      const float* __restrict__ dis,
                                                      unsigned short* __restrict__ outbf,
                                                      int n, int nst) {
    __shared__ __align__(16) unsigned short At[2][64 * 128];  // 2 x 16KB, swizzled
    const int tid = threadIdx.x;
    const int lane = tid & 63;
    const int wv = tid >> 6;
    const int col16 = lane & 15;
    const int kgrp = lane >> 4;

    int st = blockIdx.x;
    if (st >= nst) return;  // uniform per block

    float4 pf[8];   // fp32 prefetch regs
    bf16x8 pb[4];   // bf16 prefetch regs

    auto LOAD = [&](int t) {
#pragma unroll
        for (int c = 0; c < 4; ++c) {
            const int idx = c * 2048 + tid * 8;
            const int row = idx >> 7;
            const int col = idx & 127;
            int grow = t * 64 + row;
            if (grow >= n) grow = n - 1;  // clamp reads; stores masked
            if constexpr (IN_BF16) {
                pb[c] = *reinterpret_cast<const bf16x8*>(
                        (const unsigned short*)Xv + (size_t)grow * D + col);
            } else {
                const float4* p = reinterpret_cast<const float4*>(
                        (const float*)Xv + (size_t)grow * D + col);
                pf[2 * c] = p[0];
                pf[2 * c + 1] = p[1];
            }
        }
    };

    LOAD(st);  // first tile in flight while W prologue runs

    // ---- W -> 32 register B-fragments ----
    bf16x8 bw[8][4];
#pragma unroll
    for (int ct = 0; ct < 8; ++ct)
#pragma unroll
        for (int kk = 0; kk < 4; ++kk)
#pragma unroll
            for (int e = 0; e < 8; ++e) {
                const int k = kk * 32 + kgrp * 8 + e;
                bw[ct][kk][e] = (short)f2bf(W[k * D + ct * 16 + col16]);
            }

    int buf = 0;
    for (;;) {
        // ---- convert + ds_write to At[buf] (elem-swizzle col ^ ((row&7)<<3)) ----
        // (first use of the prefetched regs: vmcnt wait lands here, after a full
        //  iteration of latency-hiding work)
#pragma unroll
        for (int c = 0; c < 4; ++c) {
            const int idx = c * 2048 + tid * 8;
            const int row = idx >> 7;
            const int col = idx & 127;
            bf16x8 d;
            if constexpr (IN_BF16) {
                d = pb[c];
                if (RELU) {
#pragma unroll
                    for (int e = 0; e < 8; ++e)
                        d[e] = (short)((d[e] & (short)0x8000) ? 0 : d[e]);
                }
            } else {
                const float4 f0 = pf[2 * c], f1 = pf[2 * c + 1];
                float v[8] = {f0.x, f0.y, f0.z, f0.w, f1.x, f1.y, f1.z, f1.w};
#pragma unroll
                for (int e = 0; e < 8; ++e) {
                    float f = v[e];
                    if (RELU) f = fmaxf(f, 0.0f);
                    d[e] = (short)f2bf(f);
                }
            }
            const int waddr = row * 128 + (col ^ ((row & 7) << 3));
            *reinterpret_cast<bf16x8*>(&At[buf][waddr]) = d;
        }

        __syncthreads();  // vmcnt/lgkm drain here is cheap: loads already consumed

        // ---- ds_read A-fragments: wave wv handles rows wv*16..wv*16+15 ----
        bf16x8 a[4];
#pragma unroll
        for (int kk = 0; kk < 4; ++kk) {
            const int raddr = (wv * 16 + col16) * 128 +
                              ((kk * 32 + kgrp * 8) ^ ((col16 & 7) << 3));
            a[kk] = *reinterpret_cast<const bf16x8*>(&At[buf][raddr]);
        }

        // ---- issue next tile's global loads NOW (post-barrier => they survive) ----
        const int next = st + gridDim.x;
        if (next < nst) LOAD(next);

        f32x4 acc[8];
#pragma unroll
        for (int ct = 0; ct < 8; ++ct) acc[ct] = (f32x4){0.f, 0.f, 0.f, 0.f};
#pragma unroll
        for (int kk = 0; kk < 4; ++kk)
#pragma unroll
            for (int ct = 0; ct < 8; ++ct)
                acc[ct] = __builtin_amdgcn_mfma_f32_16x16x32_bf16(a[kk], bw[ct][kk], acc[ct], 0, 0, 0);

        const int rowbase = st * 64 + wv * 16;
        float dr[4];
#pragma unroll
        for (int r = 0; r < 4; ++r) {
            const int row = rowbase + kgrp * 4 + r;
            dr[r] = (row < n) ? dis[row] : 0.0f;
        }
#pragma unroll
        for (int ct = 0; ct < 8; ++ct)
#pragma unroll
            for (int r = 0; r < 4; ++r) {
                const int row = rowbase + kgrp * 4 + r;
                if (row < n)
                    outbf[(size_t)row * D + ct * 16 + col16] = f2bf(dr[r] * acc[ct][r]);
            }

        if (next >= nst) break;
        st = next;
        buf ^= 1;
    }
}

// ---------------- gather-aggregate (pre-scaled bf16 hs, fp32 accumulate) ----------------
// 4 nodes per wave (16 lanes/node, 16B per lane):
//   out[i] = dis[i] * ( hs[i] + sum_{j in in(i)} hs[src_j] ) + b
template <bool OUT_BF16>
__global__ __launch_bounds__(256) void k_gather_agg(const unsigned short* __restrict__ hs,
                                                    const int* __restrict__ starts,
                                                    const int* __restrict__ esrc,
                                                    const float* __restrict__ dis,
                                                    const float* __restrict__ b,
                                                    void* __restrict__ outv, int n) {
    const int lane = threadIdx.x & 63;
    const int wv = threadIdx.x >> 6;
    const int grp = lane >> 4;   // 0..3 node within wave
    const int sub = lane & 15;   // 0..15 lane within node
    const int i = (blockIdx.x * 4 + wv) * 4 + grp;
    const bool active = (i < n);
    const int ic = active ? i : (n - 1);

    const float di = dis[ic];
    const int beg = starts[ic];
    const int end = starts[ic + 1];

    auto row16 = [&](int s) -> u32x4 {
        return *reinterpret_cast<const u32x4*>(hs + (size_t)s * D + sub * 8);
    };

    float acc[8];
    {   // self-loop row
        const u32x4 u = row16(ic);
#pragma unroll
        for (int e = 0; e < 4; ++e) {
            acc[2 * e] = bf_lo(u[e]);
            acc[2 * e + 1] = bf_hi(u[e]);
        }
    }

#define ACCUM(u)                              \
    _Pragma("unroll") for (int e = 0; e < 4; ++e) { \
        acc[2 * e] += bf_lo((u)[e]);          \
        acc[2 * e + 1] += bf_hi((u)[e]);      \
    }

    int j = beg;
    while (j < end) {
        const int cnt = min(end - j, 16);
        const int myedge = (sub < cnt) ? esrc[j + sub] : 0;  // coalesced chunk
        int k = 0;
        for (; k + 4 <= cnt; k += 4) {
            const int s0 = __shfl(myedge, (grp << 4) | (k + 0));
            const int s1 = __shfl(myedge, (grp << 4) | (k + 1));
            const int s2 = __shfl(myedge, (grp << 4) | (k + 2));
            const int s3 = __shfl(myedge, (grp << 4) | (k + 3));
            const u32x4 u0 = row16(s0);
            const u32x4 u1 = row16(s1);
            const u32x4 u2 = row16(s2);
            const u32x4 u3 = row16(s3);
            ACCUM(u0) ACCUM(u1) ACCUM(u2) ACCUM(u3)
        }
        for (; k < cnt; ++k) {
            const int s0 = __shfl(myedge, (grp << 4) | k);
            const u32x4 u0 = row16(s0);
            ACCUM(u0)
        }
        j += 16;
    }
#undef ACCUM

    if (!active) return;

    const float4 bv0 = reinterpret_cast<const float4*>(b)[sub * 2 + 0];
    const float4 bv1 = reinterpret_cast<const float4*>(b)[sub * 2 + 1];
    float o[8];
    o[0] = di * acc[0] + bv0.x; o[1] = di * acc[1] + bv0.y;
    o[2] = di * acc[2] + bv0.z; o[3] = di * acc[3] + bv0.w;
    o[4] = di * acc[4] + bv1.x; o[5] = di * acc[5] + bv1.y;
    o[6] = di * acc[6] + bv1.z; o[7] = di * acc[7] + bv1.w;

    if constexpr (OUT_BF16) {
        u32x4 w;
#pragma unroll
        for (int e = 0; e < 4; ++e)
            w[e] = (unsigned)f2bf(o[2 * e]) | ((unsigned)f2bf(o[2 * e + 1]) << 16);
        *reinterpret_cast<u32x4*>((unsigned short*)outv + (size_t)i * D + sub * 8) = w;
    } else {
        float4* op = reinterpret_cast<float4*>((float*)outv + (size_t)i * D + sub * 8);
        op[0] = make_float4(o[0], o[1], o[2], o[3]);
        op[1] = make_float4(o[4], o[5], o[6], o[7]);
    }
}

extern "C" void kernel_launch(void* const* d_in, const int* in_sizes, int n_in,
                              void* d_out, int out_size, void* d_ws, size_t ws_size,
                              hipStream_t stream) {
    const float* x  = (const float*)d_in[0];
    const int*   ei = (const int*)d_in[1];   // [2, E]
    const float* W1 = (const float*)d_in[2];
    const float* b1 = (const float*)d_in[3];
    const float* W2 = (const float*)d_in[4];
    const float* b2 = (const float*)d_in[5];
    float* out = (float*)d_out;

    const int n  = in_sizes[0] / D;
    const int nE = in_sizes[1] / 2;
    const int* src = ei;
    const int* dst = ei + nE;

    char* ws = (char*)d_ws;
    float*          dis    = (float*)(ws);                  // n f32
    int*            counts = (int*)(ws + (1ull  << 19));    // n i32
    int*            starts = (int*)(ws + (2ull  << 19));    // n+1 i32
    int*            esrc   = (int*)(ws + (4ull  << 19));    // nE i32 (2..4.4M)
    int*            bsum   = (int*)(ws + (6ull  << 20));    // <=128 i32
    unsigned short* hs_bf  = (unsigned short*)(ws + (8ull  << 20));  // n*128 bf16 (8..33.6M)
    int*            rank   = (int*)(ws + (34ull << 20));    // nE i32 (34..36.4M)
    unsigned short* agg_bf = (unsigned short*)(ws + (40ull << 20));  // n*128 bf16

    const int B = 256;
    const int gn = (n + B - 1) / B;
    const int ge4 = (nE + B * 4 - 1) / (B * 4);
    const int nB = (n + 1023) / 1024;  // <=128 for n<=131072

    // CSR by dst (counts also yields degrees: deg = counts + 1 self-loop)
    k_zero1<<<gn, B, 0, stream>>>(counts, n);
    k_hist_rank<<<ge4, B, 0, stream>>>(dst, counts, rank, nE);
    k_scan_part<<<nB, B, 0, stream>>>(counts, bsum, dis, n);
    k_scan_final<<<nB, B, 0, stream>>>(counts, bsum, starts, n, nB);
    k_scatter_nr<<<ge4, B, 0, stream>>>(src, dst, rank, starts, esrc, nE);

    const int nst = (n + 63) / 64;
    const int gemm_blocks = 512;  // 2 blocks/CU, grid-stride with post-barrier prefetch
    const int agg_grid = (n + 15) / 16;

    // ---- layer 1 ----
    k_gemm_mfma<false, false><<<gemm_blocks, B, 0, stream>>>(x, W1, dis, hs_bf, n, nst);
    k_gather_agg<true><<<agg_grid, B, 0, stream>>>(hs_bf, starts, esrc, dis, b1, agg_bf, n);

    // ---- layer 2 (ReLU fused into bf16 staging; hs_bf reused) ----
    k_gemm_mfma<true, true><<<gemm_blocks, B, 0, stream>>>(agg_bf, W2, dis, hs_bf, n, nst);
    k_gather_agg<false><<<agg_grid, B, 0, stream>>>(hs_bf, starts, esrc, dis, b2, out, n);
}

// Round 9
// 157.962 us; speedup vs baseline: 5.2532x; 1.0917x over previous
//
#include <hip/hip_runtime.h>

#define D 128

typedef __attribute__((ext_vector_type(8))) short bf16x8;
typedef __attribute__((ext_vector_type(4))) float f32x4;
typedef __attribute__((ext_vector_type(4))) unsigned u32x4;

__device__ inline unsigned short f2bf(float f) {  // RNE fp32->bf16
    unsigned u = __builtin_bit_cast(unsigned, f);
    u += 0x7FFFu + ((u >> 16) & 1u);
    return (unsigned short)(u >> 16);
}
__device__ inline float bf_lo(unsigned u) { return __builtin_bit_cast(float, u << 16); }
__device__ inline float bf_hi(unsigned u) { return __builtin_bit_cast(float, u & 0xFFFF0000u); }

// ---------------- CSR build (by dst) ----------------
__global__ void k_zero1(int* __restrict__ a, int n) {
    int i = blockIdx.x * blockDim.x + threadIdx.x;
    if (i < n) a[i] = 0;
}

// Histogram that also records each edge's rank within its dst segment.
__global__ void k_hist_rank(const int* __restrict__ dst, int* __restrict__ counts,
                            int* __restrict__ rank, int nE) {
    int e4 = (blockIdx.x * blockDim.x + threadIdx.x) * 4;
    if (e4 + 4 <= nE) {
        const int4 d = *reinterpret_cast<const int4*>(dst + e4);
        int4 r;
        r.x = atomicAdd(&counts[d.x], 1);
        r.y = atomicAdd(&counts[d.y], 1);
        r.z = atomicAdd(&counts[d.z], 1);
        r.w = atomicAdd(&counts[d.w], 1);
        *reinterpret_cast<int4*>(rank + e4) = r;
    } else {
        for (int e = e4; e < nE; ++e) rank[e] = atomicAdd(&counts[dst[e]], 1);
    }
}

// Pass 1: per-block (1024-element tile) sums; fused dis = rsqrt(counts+1).
__global__ __launch_bounds__(256) void k_scan_part(const int* __restrict__ counts,
                                                   int* __restrict__ bsum,
                                                   float* __restrict__ dis, int n) {
    const int t = threadIdx.x;
    const int base = blockIdx.x * 1024 + t * 4;
    int4 c = make_int4(0, 0, 0, 0);
    if (base + 4 <= n) {
        c = *reinterpret_cast<const int4*>(counts + base);
        float4 dv;
        dv.x = rsqrtf((float)(c.x + 1));
        dv.y = rsqrtf((float)(c.y + 1));
        dv.z = rsqrtf((float)(c.z + 1));
        dv.w = rsqrtf((float)(c.w + 1));
        *reinterpret_cast<float4*>(dis + base) = dv;
    } else if (base < n) {
        int cc[4] = {0, 0, 0, 0};
        for (int k = 0; k < 4; ++k)
            if (base + k < n) {
                cc[k] = counts[base + k];
                dis[base + k] = rsqrtf((float)(cc[k] + 1));
            }
        c.x = cc[0]; c.y = cc[1]; c.z = cc[2]; c.w = cc[3];
    }
    __shared__ int red[256];
    red[t] = c.x + c.y + c.z + c.w;
    __syncthreads();
    for (int off = 128; off > 0; off >>= 1) {
        if (t < off) red[t] += red[t + off];
        __syncthreads();
    }
    if (t == 0) bsum[blockIdx.x] = red[0];
}

// Pass 2: scan block sums in LDS, local-scan tile, write starts.
__global__ __launch_bounds__(256) void k_scan_final(const int* __restrict__ counts,
                                                    const int* __restrict__ bsum,
                                                    int* __restrict__ starts, int n, int nB) {
    __shared__ int sb[128];
    __shared__ int ts[256];
    const int t = threadIdx.x;
    const int b = blockIdx.x;

    if (t < 128) sb[t] = (t < nB) ? bsum[t] : 0;
    __syncthreads();
    for (int off = 1; off < 128; off <<= 1) {
        int add = (t < 128 && t >= off) ? sb[t - off] : 0;
        __syncthreads();
        if (t < 128) sb[t] += add;
        __syncthreads();
    }
    const int block_off = (b > 0) ? sb[b - 1] : 0;

    const int base = b * 1024 + t * 4;
    int4 c = make_int4(0, 0, 0, 0);
    if (base + 4 <= n) {
        c = *reinterpret_cast<const int4*>(counts + base);
    } else if (base < n) {
        if (base + 0 < n) c.x = counts[base + 0];
        if (base + 1 < n) c.y = counts[base + 1];
        if (base + 2 < n) c.z = counts[base + 2];
    }
    const int s = c.x + c.y + c.z + c.w;
    ts[t] = s;
    __syncthreads();
    for (int off = 1; off < 256; off <<= 1) {
        int add = (t >= off) ? ts[t - off] : 0;
        __syncthreads();
        ts[t] += add;
        __syncthreads();
    }
    int excl = block_off + ts[t] - s;

    int4 w;
    w.x = excl;
    w.y = w.x + c.x;
    w.z = w.y + c.y;
    w.w = w.z + c.z;
    if (base + 4 <= n) {
        *reinterpret_cast<int4*>(starts + base) = w;
    } else if (base < n) {
        if (base + 0 < n) starts[base + 0] = w.x;
        if (base + 1 < n) starts[base + 1] = w.y;
        if (base + 2 < n) starts[base + 2] = w.z;
    }
    if (b == 0 && t == 0) starts[n] = sb[nB - 1];  // = nE
}

// Atomic-free scatter: position = starts[dst] + precomputed rank.
__global__ void k_scatter_nr(const int* __restrict__ src, const int* __restrict__ dst,
                             const int* __restrict__ rank, const int* __restrict__ starts,
                             int* __restrict__ esrc, int nE) {
    int e4 = (blockIdx.x * blockDim.x + threadIdx.x) * 4;
    if (e4 + 4 <= nE) {
        const int4 s = *reinterpret_cast<const int4*>(src + e4);
        const int4 d = *reinterpret_cast<const int4*>(dst + e4);
        const int4 r = *reinterpret_cast<const int4*>(rank + e4);
        esrc[starts[d.x] + r.x] = s.x;
        esrc[starts[d.y] + r.y] = s.y;
        esrc[starts[d.z] + r.z] = s.z;
        esrc[starts[d.w] + r.w] = s.w;
    } else {
        for (int e = e4; e < nE; ++e)
            esrc[starts[dst[e]] + rank[e]] = src[e];
    }
}

// ---------------- W pre-pack: fragment-ordered bf16 ----------------
// wp[frag=ct*4+kk][lane][e] = bf16(W[kk*32 + (lane>>4)*8 + e][ct*16 + (lane&15)])
// 32 frags x 64 lanes x 16B = 32KB. GEMM prologue then = 32 coalesced 16B loads.
__global__ __launch_bounds__(256) void k_pack_w(const float* __restrict__ W,
                                                unsigned short* __restrict__ wp) {
    const int t = blockIdx.x * blockDim.x + threadIdx.x;  // 0..2047
    const int lane = t & 63;
    const int frag = t >> 6;  // 0..31
    const int ct = frag >> 2;
    const int kk = frag & 3;
    const int col16 = lane & 15;
    const int kgrp = lane >> 4;
    bf16x8 d;
#pragma unroll
    for (int e = 0; e < 8; ++e)
        d[e] = (short)f2bf(W[(kk * 32 + kgrp * 8 + e) * D + ct * 16 + col16]);
    *reinterpret_cast<bf16x8*>(wp + (size_t)t * 8) = d;
}

// ---------------- MFMA GEMM: hs_bf16[n,128] = dis .* ((relu?)(X) @ W) ----------------
// One 64-row tile per block (grid = nst). W from prepacked fragments (32 coalesced
// loads). MFMA operands SWAPPED: mfma(bw, a, acc) computes (X@W)^T with identical
// register bytes, so D-layout is lane=node / reg=4 consecutive features -> C-write
// is 8 packed 8B stores and dis[node] is a single per-lane load.
template <bool IN_BF16, bool RELU>
__global__ __launch_bounds__(256, 2) void k_gemm_mfma(const void* __restrict__ Xv,
                                                      const unsigned short* __restrict__ wp,
                                                      const float* __restrict__ dis,
                                                      unsigned short* __restrict__ outbf,
                                                      int n) {
    __shared__ __align__(16) unsigned short At[64 * 128];  // 16KB, swizzled
    const int tid = threadIdx.x;
    const int lane = tid & 63;
    const int wv = tid >> 6;
    const int col16 = lane & 15;
    const int kgrp = lane >> 4;
    const int st = blockIdx.x;

    // ---- issue A-tile loads first (longest latency: L3/HBM) ----
    float4 pf[8];
    bf16x8 pb[4];
#pragma unroll
    for (int c = 0; c < 4; ++c) {
        const int idx = c * 2048 + tid * 8;
        const int row = idx >> 7;
        const int col = idx & 127;
        int grow = st * 64 + row;
        if (grow >= n) grow = n - 1;  // clamp reads; stores masked
        if constexpr (IN_BF16) {
            pb[c] = *reinterpret_cast<const bf16x8*>(
                    (const unsigned short*)Xv + (size_t)grow * D + col);
        } else {
            const float4* p = reinterpret_cast<const float4*>(
                    (const float*)Xv + (size_t)grow * D + col);
            pf[2 * c] = p[0];
            pf[2 * c + 1] = p[1];
        }
    }

    // ---- W fragments: 32 coalesced 16B loads (L2-resident, no conversion) ----
    bf16x8 bw[8][4];
#pragma unroll
    for (int ct = 0; ct < 8; ++ct)
#pragma unroll
        for (int kk = 0; kk < 4; ++kk)
            bw[ct][kk] = *reinterpret_cast<const bf16x8*>(
                    wp + (size_t)((ct * 4 + kk) * 64 + lane) * 8);

    // ---- convert + ds_write (elem-swizzle col ^ ((row&7)<<3)) ----
#pragma unroll
    for (int c = 0; c < 4; ++c) {
        const int idx = c * 2048 + tid * 8;
        const int row = idx >> 7;
        const int col = idx & 127;
        bf16x8 d;
        if constexpr (IN_BF16) {
            d = pb[c];
            if (RELU) {
#pragma unroll
                for (int e = 0; e < 8; ++e)
                    d[e] = (short)((d[e] & (short)0x8000) ? 0 : d[e]);
            }
        } else {
            const float4 f0 = pf[2 * c], f1 = pf[2 * c + 1];
            float v[8] = {f0.x, f0.y, f0.z, f0.w, f1.x, f1.y, f1.z, f1.w};
#pragma unroll
            for (int e = 0; e < 8; ++e) {
                float f = v[e];
                if (RELU) f = fmaxf(f, 0.0f);
                d[e] = (short)f2bf(f);
            }
        }
        const int waddr = row * 128 + (col ^ ((row & 7) << 3));
        *reinterpret_cast<bf16x8*>(&At[waddr]) = d;
    }
    __syncthreads();

    // ---- ds_read X-fragments: wave wv handles rows wv*16..wv*16+15 ----
    bf16x8 a[4];
#pragma unroll
    for (int kk = 0; kk < 4; ++kk) {
        const int raddr = (wv * 16 + col16) * 128 +
                          ((kk * 32 + kgrp * 8) ^ ((col16 & 7) << 3));
        a[kk] = *reinterpret_cast<const bf16x8*>(&At[raddr]);
    }

    f32x4 acc[8];
#pragma unroll
    for (int ct = 0; ct < 8; ++ct) acc[ct] = (f32x4){0.f, 0.f, 0.f, 0.f};
#pragma unroll
    for (int kk = 0; kk < 4; ++kk)
#pragma unroll
        for (int ct = 0; ct < 8; ++ct)  // SWAPPED operands: D = (X@W)^T
            acc[ct] = __builtin_amdgcn_mfma_f32_16x16x32_bf16(bw[ct][kk], a[kk], acc[ct], 0, 0, 0);

    // ---- C-write: lane owns node = tile_row + col16; 4 consecutive feats per reg ----
    const int node = st * 64 + wv * 16 + col16;
    if (node < n) {
        const float dn = dis[node];
        unsigned short* op = outbf + (size_t)node * D + kgrp * 4;
#pragma unroll
        for (int ct = 0; ct < 8; ++ct) {
            uint2 w;
            w.x = (unsigned)f2bf(dn * acc[ct][0]) | ((unsigned)f2bf(dn * acc[ct][1]) << 16);
            w.y = (unsigned)f2bf(dn * acc[ct][2]) | ((unsigned)f2bf(dn * acc[ct][3]) << 16);
            *reinterpret_cast<uint2*>(op + ct * 16) = w;
        }
    }
}

// ---------------- gather-aggregate (pre-scaled bf16 hs, fp32 accumulate) ----------------
// 4 nodes per wave (16 lanes/node, 16B per lane):
//   out[i] = dis[i] * ( hs[i] + sum_{j in in(i)} hs[src_j] ) + b
template <bool OUT_BF16>
__global__ __launch_bounds__(256) void k_gather_agg(const unsigned short* __restrict__ hs,
                                                    const int* __restrict__ starts,
                                                    const int* __restrict__ esrc,
                                                    const float* __restrict__ dis,
                                                    const float* __restrict__ b,
                                                    void* __restrict__ outv, int n) {
    const int lane = threadIdx.x & 63;
    const int wv = threadIdx.x >> 6;
    const int grp = lane >> 4;   // 0..3 node within wave
    const int sub = lane & 15;   // 0..15 lane within node
    const int i = (blockIdx.x * 4 + wv) * 4 + grp;
    const bool active = (i < n);
    const int ic = active ? i : (n - 1);

    const float di = dis[ic];
    const int beg = starts[ic];
    const int end = starts[ic + 1];

    auto row16 = [&](int s) -> u32x4 {
        return *reinterpret_cast<const u32x4*>(hs + (size_t)s * D + sub * 8);
    };

    float acc[8];
    {   // self-loop row
        const u32x4 u = row16(ic);
#pragma unroll
        for (int e = 0; e < 4; ++e) {
            acc[2 * e] = bf_lo(u[e]);
            acc[2 * e + 1] = bf_hi(u[e]);
        }
    }

#define ACCUM(u)                              \
    _Pragma("unroll") for (int e = 0; e < 4; ++e) { \
        acc[2 * e] += bf_lo((u)[e]);          \
        acc[2 * e + 1] += bf_hi((u)[e]);      \
    }

    int j = beg;
    while (j < end) {
        const int cnt = min(end - j, 16);
        const int myedge = (sub < cnt) ? esrc[j + sub] : 0;  // coalesced chunk
        int k = 0;
        for (; k + 4 <= cnt; k += 4) {
            const int s0 = __shfl(myedge, (grp << 4) | (k + 0));
            const int s1 = __shfl(myedge, (grp << 4) | (k + 1));
            const int s2 = __shfl(myedge, (grp << 4) | (k + 2));
            const int s3 = __shfl(myedge, (grp << 4) | (k + 3));
            const u32x4 u0 = row16(s0);
            const u32x4 u1 = row16(s1);
            const u32x4 u2 = row16(s2);
            const u32x4 u3 = row16(s3);
            ACCUM(u0) ACCUM(u1) ACCUM(u2) ACCUM(u3)
        }
        for (; k < cnt; ++k) {
            const int s0 = __shfl(myedge, (grp << 4) | k);
            const u32x4 u0 = row16(s0);
            ACCUM(u0)
        }
        j += 16;
    }
#undef ACCUM

    if (!active) return;

    const float4 bv0 = reinterpret_cast<const float4*>(b)[sub * 2 + 0];
    const float4 bv1 = reinterpret_cast<const float4*>(b)[sub * 2 + 1];
    float o[8];
    o[0] = di * acc[0] + bv0.x; o[1] = di * acc[1] + bv0.y;
    o[2] = di * acc[2] + bv0.z; o[3] = di * acc[3] + bv0.w;
    o[4] = di * acc[4] + bv1.x; o[5] = di * acc[5] + bv1.y;
    o[6] = di * acc[6] + bv1.z; o[7] = di * acc[7] + bv1.w;

    if constexpr (OUT_BF16) {
        u32x4 w;
#pragma unroll
        for (int e = 0; e < 4; ++e)
            w[e] = (unsigned)f2bf(o[2 * e]) | ((unsigned)f2bf(o[2 * e + 1]) << 16);
        *reinterpret_cast<u32x4*>((unsigned short*)outv + (size_t)i * D + sub * 8) = w;
    } else {
        float4* op = reinterpret_cast<float4*>((float*)outv + (size_t)i * D + sub * 8);
        op[0] = make_float4(o[0], o[1], o[2], o[3]);
        op[1] = make_float4(o[4], o[5], o[6], o[7]);
    }
}

extern "C" void kernel_launch(void* const* d_in, const int* in_sizes, int n_in,
                              void* d_out, int out_size, void* d_ws, size_t ws_size,
                              hipStream_t stream) {
    const float* x  = (const float*)d_in[0];
    const int*   ei = (const int*)d_in[1];   // [2, E]
    const float* W1 = (const float*)d_in[2];
    const float* b1 = (const float*)d_in[3];
    const float* W2 = (const float*)d_in[4];
    const float* b2 = (const float*)d_in[5];
    float* out = (float*)d_out;

    const int n  = in_sizes[0] / D;
    const int nE = in_sizes[1] / 2;
    const int* src = ei;
    const int* dst = ei + nE;

    char* ws = (char*)d_ws;
    float*          dis    = (float*)(ws);                  // n f32
    int*            counts = (int*)(ws + (1ull  << 19));    // n i32
    int*            starts = (int*)(ws + (2ull  << 19));    // n+1 i32
    int*            esrc   = (int*)(ws + (4ull  << 19));    // nE i32 (2..4.4M)
    int*            bsum   = (int*)(ws + (6ull  << 20));    // <=128 i32
    unsigned short* hs_bf  = (unsigned short*)(ws + (8ull  << 20));  // n*128 bf16 (8..33.6M)
    int*            rank   = (int*)(ws + (34ull << 20));    // nE i32 (34..36.4M)
    unsigned short* wp1    = (unsigned short*)(ws + (37ull << 20));  // 32KB
    unsigned short* wp2    = (unsigned short*)(ws + (37ull << 20) + (1ull << 15));
    unsigned short* agg_bf = (unsigned short*)(ws + (40ull << 20));  // n*128 bf16

    const int B = 256;
    const int gn = (n + B - 1) / B;
    const int ge4 = (nE + B * 4 - 1) / (B * 4);
    const int nB = (n + 1023) / 1024;  // <=128 for n<=131072

    // W pre-pack (independent; issue first so it's done before the GEMMs)
    k_pack_w<<<8, B, 0, stream>>>(W1, wp1);
    k_pack_w<<<8, B, 0, stream>>>(W2, wp2);

    // CSR by dst (counts also yields degrees: deg = counts + 1 self-loop)
    k_zero1<<<gn, B, 0, stream>>>(counts, n);
    k_hist_rank<<<ge4, B, 0, stream>>>(dst, counts, rank, nE);
    k_scan_part<<<nB, B, 0, stream>>>(counts, bsum, dis, n);
    k_scan_final<<<nB, B, 0, stream>>>(counts, bsum, starts, n, nB);
    k_scatter_nr<<<ge4, B, 0, stream>>>(src, dst, rank, starts, esrc, nE);

    const int nst = (n + 63) / 64;
    const int agg_grid = (n + 15) / 16;

    // ---- layer 1 ----
    k_gemm_mfma<false, false><<<nst, B, 0, stream>>>(x, wp1, dis, hs_bf, n);
    k_gather_agg<true><<<agg_grid, B, 0, stream>>>(hs_bf, starts, esrc, dis, b1, agg_bf, n);

    // ---- layer 2 (ReLU fused into bf16 staging; hs_bf reused) ----
    k_gemm_mfma<true, true><<<nst, B, 0, stream>>>(agg_bf, wp2, dis, hs_bf, n);
    k_gather_agg<false><<<agg_grid, B, 0, stream>>>(hs_bf, starts, esrc, dis, b2, out, n);
}

// Round 10
// 147.715 us; speedup vs baseline: 5.6176x; 1.0694x over previous
//
#include <hip/hip_runtime.h>

#define D 128

typedef __attribute__((ext_vector_type(8))) short bf16x8;
typedef __attribute__((ext_vector_type(4))) float f32x4;
typedef __attribute__((ext_vector_type(4))) unsigned u32x4;

__device__ inline unsigned short f2bf(float f) {  // RNE fp32->bf16
    unsigned u = __builtin_bit_cast(unsigned, f);
    u += 0x7FFFu + ((u >> 16) & 1u);
    return (unsigned short)(u >> 16);
}
__device__ inline float bf_lo(unsigned u) { return __builtin_bit_cast(float, u << 16); }
__device__ inline float bf_hi(unsigned u) { return __builtin_bit_cast(float, u & 0xFFFF0000u); }

// ---------------- CSR build (by dst) ----------------
__global__ void k_zero1(int* __restrict__ a, int n) {
    int i = blockIdx.x * blockDim.x + threadIdx.x;
    if (i < n) a[i] = 0;
}

// Histogram that also records each edge's rank within its dst segment.
__global__ void k_hist_rank(const int* __restrict__ dst, int* __restrict__ counts,
                            int* __restrict__ rank, int nE) {
    int e4 = (blockIdx.x * blockDim.x + threadIdx.x) * 4;
    if (e4 + 4 <= nE) {
        const int4 d = *reinterpret_cast<const int4*>(dst + e4);
        int4 r;
        r.x = atomicAdd(&counts[d.x], 1);
        r.y = atomicAdd(&counts[d.y], 1);
        r.z = atomicAdd(&counts[d.z], 1);
        r.w = atomicAdd(&counts[d.w], 1);
        *reinterpret_cast<int4*>(rank + e4) = r;
    } else {
        for (int e = e4; e < nE; ++e) rank[e] = atomicAdd(&counts[dst[e]], 1);
    }
}

// Pass 1: per-block (1024-element tile) sums; fused dis = rsqrt(counts+1).
__global__ __launch_bounds__(256) void k_scan_part(const int* __restrict__ counts,
                                                   int* __restrict__ bsum,
                                                   float* __restrict__ dis, int n) {
    const int t = threadIdx.x;
    const int base = blockIdx.x * 1024 + t * 4;
    int4 c = make_int4(0, 0, 0, 0);
    if (base + 4 <= n) {
        c = *reinterpret_cast<const int4*>(counts + base);
        float4 dv;
        dv.x = rsqrtf((float)(c.x + 1));
        dv.y = rsqrtf((float)(c.y + 1));
        dv.z = rsqrtf((float)(c.z + 1));
        dv.w = rsqrtf((float)(c.w + 1));
        *reinterpret_cast<float4*>(dis + base) = dv;
    } else if (base < n) {
        int cc[4] = {0, 0, 0, 0};
        for (int k = 0; k < 4; ++k)
            if (base + k < n) {
                cc[k] = counts[base + k];
                dis[base + k] = rsqrtf((float)(cc[k] + 1));
            }
        c.x = cc[0]; c.y = cc[1]; c.z = cc[2]; c.w = cc[3];
    }
    __shared__ int red[256];
    red[t] = c.x + c.y + c.z + c.w;
    __syncthreads();
    for (int off = 128; off > 0; off >>= 1) {
        if (t < off) red[t] += red[t + off];
        __syncthreads();
    }
    if (t == 0) bsum[blockIdx.x] = red[0];
}

// Pass 2: scan block sums in LDS, local-scan tile, write starts.
__global__ __launch_bounds__(256) void k_scan_final(const int* __restrict__ counts,
                                                    const int* __restrict__ bsum,
                                                    int* __restrict__ starts, int n, int nB) {
    __shared__ int sb[128];
    __shared__ int ts[256];
    const int t = threadIdx.x;
    const int b = blockIdx.x;

    if (t < 128) sb[t] = (t < nB) ? bsum[t] : 0;
    __syncthreads();
    for (int off = 1; off < 128; off <<= 1) {
        int add = (t < 128 && t >= off) ? sb[t - off] : 0;
        __syncthreads();
        if (t < 128) sb[t] += add;
        __syncthreads();
    }
    const int block_off = (b > 0) ? sb[b - 1] : 0;

    const int base = b * 1024 + t * 4;
    int4 c = make_int4(0, 0, 0, 0);
    if (base + 4 <= n) {
        c = *reinterpret_cast<const int4*>(counts + base);
    } else if (base < n) {
        if (base + 0 < n) c.x = counts[base + 0];
        if (base + 1 < n) c.y = counts[base + 1];
        if (base + 2 < n) c.z = counts[base + 2];
    }
    const int s = c.x + c.y + c.z + c.w;
    ts[t] = s;
    __syncthreads();
    for (int off = 1; off < 256; off <<= 1) {
        int add = (t >= off) ? ts[t - off] : 0;
        __syncthreads();
        ts[t] += add;
        __syncthreads();
    }
    int excl = block_off + ts[t] - s;

    int4 w;
    w.x = excl;
    w.y = w.x + c.x;
    w.z = w.y + c.y;
    w.w = w.z + c.z;
    if (base + 4 <= n) {
        *reinterpret_cast<int4*>(starts + base) = w;
    } else if (base < n) {
        if (base + 0 < n) starts[base + 0] = w.x;
        if (base + 1 < n) starts[base + 1] = w.y;
        if (base + 2 < n) starts[base + 2] = w.z;
    }
    if (b == 0 && t == 0) starts[n] = sb[nB - 1];  // = nE
}

// Atomic-free scatter: position = starts[dst] + precomputed rank.
__global__ void k_scatter_nr(const int* __restrict__ src, const int* __restrict__ dst,
                             const int* __restrict__ rank, const int* __restrict__ starts,
                             int* __restrict__ esrc, int nE) {
    int e4 = (blockIdx.x * blockDim.x + threadIdx.x) * 4;
    if (e4 + 4 <= nE) {
        const int4 s = *reinterpret_cast<const int4*>(src + e4);
        const int4 d = *reinterpret_cast<const int4*>(dst + e4);
        const int4 r = *reinterpret_cast<const int4*>(rank + e4);
        esrc[starts[d.x] + r.x] = s.x;
        esrc[starts[d.y] + r.y] = s.y;
        esrc[starts[d.z] + r.z] = s.z;
        esrc[starts[d.w] + r.w] = s.w;
    } else {
        for (int e = e4; e < nE; ++e)
            esrc[starts[dst[e]] + rank[e]] = src[e];
    }
}

// ---------------- W pre-pack (both layers in one launch) ----------------
// wp[t=frag*64+lane] layout: frag=ct*4+kk; lane gives (col16,kgrp).
__global__ __launch_bounds__(256) void k_pack_w2(const float* __restrict__ W1,
                                                 const float* __restrict__ W2,
                                                 unsigned short* __restrict__ wp) {
    const int t = blockIdx.x * blockDim.x + threadIdx.x;  // 0..4095
    const float* W = (t < 2048) ? W1 : W2;
    const int tt = t & 2047;
    const int lane = tt & 63;
    const int frag = tt >> 6;  // 0..31
    const int ct = frag >> 2;
    const int kk = frag & 3;
    const int col16 = lane & 15;
    const int kgrp = lane >> 4;
    bf16x8 d;
#pragma unroll
    for (int e = 0; e < 8; ++e)
        d[e] = (short)f2bf(W[(kk * 32 + kgrp * 8 + e) * D + ct * 16 + col16]);
    *reinterpret_cast<bf16x8*>(wp + (size_t)t * 8) = d;
}

// ---------------- shared gather core: acc[8] = hs[ic] + sum hs[esrc[beg..end)] ----
// 16 lanes per node (grp selects node in wave, sub = lane within node, 16B/lane).
// 8-deep load pipeline with clamped-duplicate indices (dupes = L1 hits).
__device__ __forceinline__ void gather_rows(const unsigned short* __restrict__ hs,
                                            const int* __restrict__ esrc,
                                            int beg, int end, int grp, int sub, int ic,
                                            float acc[8]) {
    auto row16 = [&](int s) -> u32x4 {
        return *reinterpret_cast<const u32x4*>(hs + (size_t)s * D + sub * 8);
    };
    {   // self-loop row
        const u32x4 u = row16(ic);
#pragma unroll
        for (int e = 0; e < 4; ++e) {
            acc[2 * e] = bf_lo(u[e]);
            acc[2 * e + 1] = bf_hi(u[e]);
        }
    }
    int j = beg;
    while (j < end) {
        const int cnt = min(end - j, 16);
        const int myedge = (sub < cnt) ? esrc[j + sub] : 0;  // coalesced chunk
        for (int k = 0; k < cnt; k += 8) {
            u32x4 u[8];
#pragma unroll
            for (int q = 0; q < 8; ++q) {
                const int tq = min(k + q, cnt - 1);  // clamp: dupes hit L1
                const int s = __shfl(myedge, (grp << 4) | tq);
                u[q] = row16(s);
            }
            const int rem = cnt - k;
#pragma unroll
            for (int q = 0; q < 8; ++q) {
                if (q < rem) {
#pragma unroll
                    for (int e = 0; e < 4; ++e) {
                        acc[2 * e] += bf_lo(u[q][e]);
                        acc[2 * e + 1] += bf_hi(u[q][e]);
                    }
                }
            }
        }
        j += 16;
    }
}

// ---------------- MFMA GEMM (layer 1): hs_bf16[n,128] = dis .* (X @ W) ----------------
// One 64-row tile per block. W frags loaded in two ct-halves (peak VGPR -64);
// swapped MFMA operands -> lane=node D-layout, packed 8B stores.
template <bool IN_BF16, bool RELU>
__global__ __launch_bounds__(256, 3) void k_gemm_mfma(const void* __restrict__ Xv,
                                                      const unsigned short* __restrict__ wp,
                                                      const float* __restrict__ dis,
                                                      unsigned short* __restrict__ outbf,
                                                      int n) {
    __shared__ __align__(16) unsigned short At[64 * 128];  // 16KB, swizzled
    const int tid = threadIdx.x;
    const int lane = tid & 63;
    const int wv = tid >> 6;
    const int col16 = lane & 15;
    const int kgrp = lane >> 4;
    const int st = blockIdx.x;

    // ---- issue A-tile loads first (longest latency) ----
    float4 pf[8];
    bf16x8 pb[4];
#pragma unroll
    for (int c = 0; c < 4; ++c) {
        const int idx = c * 2048 + tid * 8;
        const int row = idx >> 7;
        const int col = idx & 127;
        int grow = st * 64 + row;
        if (grow >= n) grow = n - 1;  // clamp reads; stores masked
        if constexpr (IN_BF16) {
            pb[c] = *reinterpret_cast<const bf16x8*>(
                    (const unsigned short*)Xv + (size_t)grow * D + col);
        } else {
            const float4* p = reinterpret_cast<const float4*>(
                    (const float*)Xv + (size_t)grow * D + col);
            pf[2 * c] = p[0];
            pf[2 * c + 1] = p[1];
        }
    }

    // ---- convert + ds_write (elem-swizzle col ^ ((row&7)<<3)) ----
#pragma unroll
    for (int c = 0; c < 4; ++c) {
        const int idx = c * 2048 + tid * 8;
        const int row = idx >> 7;
        const int col = idx & 127;
        bf16x8 d;
        if constexpr (IN_BF16) {
            d = pb[c];
            if (RELU) {
#pragma unroll
                for (int e = 0; e < 8; ++e)
                    d[e] = (short)((d[e] & (short)0x8000) ? 0 : d[e]);
            }
        } else {
            const float4 f0 = pf[2 * c], f1 = pf[2 * c + 1];
            float v[8] = {f0.x, f0.y, f0.z, f0.w, f1.x, f1.y, f1.z, f1.w};
#pragma unroll
            for (int e = 0; e < 8; ++e) {
                float f = v[e];
                if (RELU) f = fmaxf(f, 0.0f);
                d[e] = (short)f2bf(f);
            }
        }
        const int waddr = row * 128 + (col ^ ((row & 7) << 3));
        *reinterpret_cast<bf16x8*>(&At[waddr]) = d;
    }
    __syncthreads();

    // ---- ds_read X-fragments ----
    bf16x8 a[4];
#pragma unroll
    for (int kk = 0; kk < 4; ++kk) {
        const int raddr = (wv * 16 + col16) * 128 +
                          ((kk * 32 + kgrp * 8) ^ ((col16 & 7) << 3));
        a[kk] = *reinterpret_cast<const bf16x8*>(&At[raddr]);
    }

    const int node = st * 64 + wv * 16 + col16;
    const float dn = (node < n) ? dis[node] : 0.0f;
    unsigned short* op = outbf + (size_t)node * D + kgrp * 4;

    // ---- two ct-halves: load 16 W frags, 16 MFMA, store 4 cts ----
#pragma unroll
    for (int h = 0; h < 2; ++h) {
        bf16x8 bw[4][4];
#pragma unroll
        for (int c2 = 0; c2 < 4; ++c2)
#pragma unroll
            for (int kk = 0; kk < 4; ++kk)
                bw[c2][kk] = *reinterpret_cast<const bf16x8*>(
                        wp + (size_t)(((h * 4 + c2) * 4 + kk) * 64 + lane) * 8);

        f32x4 acc[4];
#pragma unroll
        for (int c2 = 0; c2 < 4; ++c2) acc[c2] = (f32x4){0.f, 0.f, 0.f, 0.f};
#pragma unroll
        for (int kk = 0; kk < 4; ++kk)
#pragma unroll
            for (int c2 = 0; c2 < 4; ++c2)  // SWAPPED operands: D = (X@W)^T
                acc[c2] = __builtin_amdgcn_mfma_f32_16x16x32_bf16(bw[c2][kk], a[kk], acc[c2], 0, 0, 0);

        if (node < n) {
#pragma unroll
            for (int c2 = 0; c2 < 4; ++c2) {
                uint2 w;
                w.x = (unsigned)f2bf(dn * acc[c2][0]) | ((unsigned)f2bf(dn * acc[c2][1]) << 16);
                w.y = (unsigned)f2bf(dn * acc[c2][2]) | ((unsigned)f2bf(dn * acc[c2][3]) << 16);
                *reinterpret_cast<uint2*>(op + (h * 4 + c2) * 16) = w;
            }
        }
    }
}

// ---------------- FUSED gather + GEMM (layer 1 agg + layer 2 matmul) ----------------
// Per block: gather 64 nodes' aggregation (bias+ReLU fused) straight into the
// swizzled LDS A-tile, then MFMA with prepacked W2, epilogue pre-scales by dis.
// Eliminates the agg_bf round-trip entirely.
__global__ __launch_bounds__(256, 3) void k_gather_gemm(const unsigned short* __restrict__ hs,
                                                        const int* __restrict__ starts,
                                                        const int* __restrict__ esrc,
                                                        const float* __restrict__ dis,
                                                        const float* __restrict__ bias,
                                                        const unsigned short* __restrict__ wp,
                                                        unsigned short* __restrict__ outbf,
                                                        int n) {
    __shared__ __align__(16) unsigned short At[64 * 128];  // 16KB, swizzled
    const int tid = threadIdx.x;
    const int lane = tid & 63;
    const int wv = tid >> 6;
    const int col16 = lane & 15;
    const int kgrp = lane >> 4;
    const int grp = lane >> 4;   // node within 4-node gather group
    const int sub = lane & 15;   // lane within node
    const int st = blockIdx.x;

    const float4 bv0 = reinterpret_cast<const float4*>(bias)[sub * 2 + 0];
    const float4 bv1 = reinterpret_cast<const float4*>(bias)[sub * 2 + 1];

    // ---- gather phase: wave wv fills rows wv*16..+15, 4 nodes per pass ----
#pragma unroll 1
    for (int p = 0; p < 4; ++p) {
        const int lrow = wv * 16 + p * 4 + grp;
        const int i = st * 64 + lrow;
        const int ic = (i < n) ? i : (n - 1);
        const float di = dis[ic];
        float acc[8];
        gather_rows(hs, esrc, starts[ic], starts[ic + 1], grp, sub, ic, acc);

        float o[8];
        o[0] = di * acc[0] + bv0.x; o[1] = di * acc[1] + bv0.y;
        o[2] = di * acc[2] + bv0.z; o[3] = di * acc[3] + bv0.w;
        o[4] = di * acc[4] + bv1.x; o[5] = di * acc[5] + bv1.y;
        o[6] = di * acc[6] + bv1.z; o[7] = di * acc[7] + bv1.w;

        u32x4 w;  // ReLU + bf16 pack
#pragma unroll
        for (int e = 0; e < 4; ++e)
            w[e] = (unsigned)f2bf(fmaxf(o[2 * e], 0.0f)) |
                   ((unsigned)f2bf(fmaxf(o[2 * e + 1], 0.0f)) << 16);
        const int waddr = lrow * 128 + ((sub * 8) ^ ((lrow & 7) << 3));
        *reinterpret_cast<u32x4*>(&At[waddr]) = w;
    }
    __syncthreads();

    // ---- GEMM phase (identical to k_gemm_mfma post-barrier) ----
    bf16x8 a[4];
#pragma unroll
    for (int kk = 0; kk < 4; ++kk) {
        const int raddr = (wv * 16 + col16) * 128 +
                          ((kk * 32 + kgrp * 8) ^ ((col16 & 7) << 3));
        a[kk] = *reinterpret_cast<const bf16x8*>(&At[raddr]);
    }

    const int node = st * 64 + wv * 16 + col16;
    const float dn = (node < n) ? dis[node] : 0.0f;
    unsigned short* op = outbf + (size_t)node * D + kgrp * 4;

#pragma unroll
    for (int h = 0; h < 2; ++h) {
        bf16x8 bw[4][4];
#pragma unroll
        for (int c2 = 0; c2 < 4; ++c2)
#pragma unroll
            for (int kk = 0; kk < 4; ++kk)
                bw[c2][kk] = *reinterpret_cast<const bf16x8*>(
                        wp + (size_t)(((h * 4 + c2) * 4 + kk) * 64 + lane) * 8);

        f32x4 acc[4];
#pragma unroll
        for (int c2 = 0; c2 < 4; ++c2) acc[c2] = (f32x4){0.f, 0.f, 0.f, 0.f};
#pragma unroll
        for (int kk = 0; kk < 4; ++kk)
#pragma unroll
            for (int c2 = 0; c2 < 4; ++c2)
                acc[c2] = __builtin_amdgcn_mfma_f32_16x16x32_bf16(bw[c2][kk], a[kk], acc[c2], 0, 0, 0);

        if (node < n) {
#pragma unroll
            for (int c2 = 0; c2 < 4; ++c2) {
                uint2 w;
                w.x = (unsigned)f2bf(dn * acc[c2][0]) | ((unsigned)f2bf(dn * acc[c2][1]) << 16);
                w.y = (unsigned)f2bf(dn * acc[c2][2]) | ((unsigned)f2bf(dn * acc[c2][3]) << 16);
                *reinterpret_cast<uint2*>(op + (h * 4 + c2) * 16) = w;
            }
        }
    }
}

// ---------------- standalone gather-aggregate (layer 2 output, f32) ----------------
__global__ __launch_bounds__(256) void k_gather_agg(const unsigned short* __restrict__ hs,
                                                    const int* __restrict__ starts,
                                                    const int* __restrict__ esrc,
                                                    const float* __restrict__ dis,
                                                    const float* __restrict__ b,
                                                    float* __restrict__ outv, int n) {
    const int lane = threadIdx.x & 63;
    const int wv = threadIdx.x >> 6;
    const int grp = lane >> 4;
    const int sub = lane & 15;
    const int i = (blockIdx.x * 4 + wv) * 4 + grp;
    const bool active = (i < n);
    const int ic = active ? i : (n - 1);

    const float di = dis[ic];
    float acc[8];
    gather_rows(hs, esrc, starts[ic], starts[ic + 1], grp, sub, ic, acc);

    if (!active) return;

    const float4 bv0 = reinterpret_cast<const float4*>(b)[sub * 2 + 0];
    const float4 bv1 = reinterpret_cast<const float4*>(b)[sub * 2 + 1];
    float4* op = reinterpret_cast<float4*>(outv + (size_t)i * D + sub * 8);
    op[0] = make_float4(di * acc[0] + bv0.x, di * acc[1] + bv0.y,
                        di * acc[2] + bv0.z, di * acc[3] + bv0.w);
    op[1] = make_float4(di * acc[4] + bv1.x, di * acc[5] + bv1.y,
                        di * acc[6] + bv1.z, di * acc[7] + bv1.w);
}

extern "C" void kernel_launch(void* const* d_in, const int* in_sizes, int n_in,
                              void* d_out, int out_size, void* d_ws, size_t ws_size,
                              hipStream_t stream) {
    const float* x  = (const float*)d_in[0];
    const int*   ei = (const int*)d_in[1];   // [2, E]
    const float* W1 = (const float*)d_in[2];
    const float* b1 = (const float*)d_in[3];
    const float* W2 = (const float*)d_in[4];
    const float* b2 = (const float*)d_in[5];
    float* out = (float*)d_out;

    const int n  = in_sizes[0] / D;
    const int nE = in_sizes[1] / 2;
    const int* src = ei;
    const int* dst = ei + nE;

    char* ws = (char*)d_ws;
    float*          dis    = (float*)(ws);                  // n f32
    int*            counts = (int*)(ws + (1ull  << 19));    // n i32
    int*            starts = (int*)(ws + (2ull  << 19));    // n+1 i32
    int*            esrc   = (int*)(ws + (4ull  << 19));    // nE i32 (2..4.4M)
    int*            bsum   = (int*)(ws + (6ull  << 20));    // <=128 i32
    unsigned short* hs_bf  = (unsigned short*)(ws + (8ull  << 20));  // n*128 bf16
    int*            rank   = (int*)(ws + (34ull << 20));    // nE i32
    unsigned short* wp     = (unsigned short*)(ws + (37ull << 20));  // 64KB (both layers)
    unsigned short* hs2_bf = (unsigned short*)(ws + (40ull << 20));  // n*128 bf16

    unsigned short* wp1 = wp;
    unsigned short* wp2 = wp + 2048 * 8;

    const int B = 256;
    const int gn = (n + B - 1) / B;
    const int ge4 = (nE + B * 4 - 1) / (B * 4);
    const int nB = (n + 1023) / 1024;  // <=128 for n<=131072

    // W pre-pack (both layers, one launch)
    k_pack_w2<<<16, B, 0, stream>>>(W1, W2, wp);

    // CSR by dst (counts also yields degrees: deg = counts + 1 self-loop)
    k_zero1<<<gn, B, 0, stream>>>(counts, n);
    k_hist_rank<<<ge4, B, 0, stream>>>(dst, counts, rank, nE);
    k_scan_part<<<nB, B, 0, stream>>>(counts, bsum, dis, n);
    k_scan_final<<<nB, B, 0, stream>>>(counts, bsum, starts, n, nB);
    k_scatter_nr<<<ge4, B, 0, stream>>>(src, dst, rank, starts, esrc, nE);

    const int nst = (n + 63) / 64;
    const int agg_grid = (n + 15) / 16;

    // ---- layer 1 GEMM: hs = dis .* (x @ W1) ----
    k_gemm_mfma<false, false><<<nst, B, 0, stream>>>(x, wp1, dis, hs_bf, n);
    // ---- FUSED: agg1(+b1,ReLU) -> @W2 -> hs2 = dis .* (relu(agg1) @ W2) ----
    k_gather_gemm<<<nst, B, 0, stream>>>(hs_bf, starts, esrc, dis, b1, wp2, hs2_bf, n);
    // ---- layer 2 aggregation -> f32 output ----
    k_gather_agg<<<agg_grid, B, 0, stream>>>(hs2_bf, starts, esrc, dis, b2, out, n);
}

// Round 11
// 144.820 us; speedup vs baseline: 5.7299x; 1.0200x over previous
//
#include <hip/hip_runtime.h>

#define D 128

typedef __attribute__((ext_vector_type(8))) short bf16x8;
typedef __attribute__((ext_vector_type(4))) float f32x4;
typedef __attribute__((ext_vector_type(4))) unsigned u32x4;

__device__ inline unsigned short f2bf(float f) {  // RNE fp32->bf16
    unsigned u = __builtin_bit_cast(unsigned, f);
    u += 0x7FFFu + ((u >> 16) & 1u);
    return (unsigned short)(u >> 16);
}
__device__ inline float bf_lo(unsigned u) { return __builtin_bit_cast(float, u << 16); }
__device__ inline float bf_hi(unsigned u) { return __builtin_bit_cast(float, u & 0xFFFF0000u); }

// ---------------- W pre-pack (both layers) + counts zero, one launch ----------------
// blocks 0..15: pack W1/W2 into MFMA fragment order; blocks 16..: zero counts.
__global__ __launch_bounds__(256) void k_pack_zero(const float* __restrict__ W1,
                                                   const float* __restrict__ W2,
                                                   unsigned short* __restrict__ wp,
                                                   int* __restrict__ counts, int n) {
    if (blockIdx.x < 16) {
        const int t = blockIdx.x * 256 + threadIdx.x;  // 0..4095
        const float* W = (t < 2048) ? W1 : W2;
        const int tt = t & 2047;
        const int lane = tt & 63;
        const int frag = tt >> 6;  // 0..31
        const int ct = frag >> 2;
        const int kk = frag & 3;
        const int col16 = lane & 15;
        const int kgrp = lane >> 4;
        bf16x8 d;
#pragma unroll
        for (int e = 0; e < 8; ++e)
            d[e] = (short)f2bf(W[(kk * 32 + kgrp * 8 + e) * D + ct * 16 + col16]);
        *reinterpret_cast<bf16x8*>(wp + (size_t)t * 8) = d;
    } else {
        const int i = (blockIdx.x - 16) * 256 + threadIdx.x;
        if (i < n) counts[i] = 0;
    }
}

// Histogram that also records each edge's rank within its dst segment.
__global__ void k_hist_rank(const int* __restrict__ dst, int* __restrict__ counts,
                            int* __restrict__ rank, int nE) {
    int e4 = (blockIdx.x * blockDim.x + threadIdx.x) * 4;
    if (e4 + 4 <= nE) {
        const int4 d = *reinterpret_cast<const int4*>(dst + e4);
        int4 r;
        r.x = atomicAdd(&counts[d.x], 1);
        r.y = atomicAdd(&counts[d.y], 1);
        r.z = atomicAdd(&counts[d.z], 1);
        r.w = atomicAdd(&counts[d.w], 1);
        *reinterpret_cast<int4*>(rank + e4) = r;
    } else {
        for (int e = e4; e < nE; ++e) rank[e] = atomicAdd(&counts[dst[e]], 1);
    }
}

// Pass 1: per-block (1024-element tile) sums; fused dis = rsqrt(counts+1).
__global__ __launch_bounds__(256) void k_scan_part(const int* __restrict__ counts,
                                                   int* __restrict__ bsum,
                                                   float* __restrict__ dis, int n) {
    const int t = threadIdx.x;
    const int base = blockIdx.x * 1024 + t * 4;
    int4 c = make_int4(0, 0, 0, 0);
    if (base + 4 <= n) {
        c = *reinterpret_cast<const int4*>(counts + base);
        float4 dv;
        dv.x = rsqrtf((float)(c.x + 1));
        dv.y = rsqrtf((float)(c.y + 1));
        dv.z = rsqrtf((float)(c.z + 1));
        dv.w = rsqrtf((float)(c.w + 1));
        *reinterpret_cast<float4*>(dis + base) = dv;
    } else if (base < n) {
        int cc[4] = {0, 0, 0, 0};
        for (int k = 0; k < 4; ++k)
            if (base + k < n) {
                cc[k] = counts[base + k];
                dis[base + k] = rsqrtf((float)(cc[k] + 1));
            }
        c.x = cc[0]; c.y = cc[1]; c.z = cc[2]; c.w = cc[3];
    }
    __shared__ int red[256];
    red[t] = c.x + c.y + c.z + c.w;
    __syncthreads();
    for (int off = 128; off > 0; off >>= 1) {
        if (t < off) red[t] += red[t + off];
        __syncthreads();
    }
    if (t == 0) bsum[blockIdx.x] = red[0];
}

// Pass 2: scan block sums in LDS, local-scan tile, write starts.
__global__ __launch_bounds__(256) void k_scan_final(const int* __restrict__ counts,
                                                    const int* __restrict__ bsum,
                                                    int* __restrict__ starts, int n, int nB) {
    __shared__ int sb[128];
    __shared__ int ts[256];
    const int t = threadIdx.x;
    const int b = blockIdx.x;

    if (t < 128) sb[t] = (t < nB) ? bsum[t] : 0;
    __syncthreads();
    for (int off = 1; off < 128; off <<= 1) {
        int add = (t < 128 && t >= off) ? sb[t - off] : 0;
        __syncthreads();
        if (t < 128) sb[t] += add;
        __syncthreads();
    }
    const int block_off = (b > 0) ? sb[b - 1] : 0;

    const int base = b * 1024 + t * 4;
    int4 c = make_int4(0, 0, 0, 0);
    if (base + 4 <= n) {
        c = *reinterpret_cast<const int4*>(counts + base);
    } else if (base < n) {
        if (base + 0 < n) c.x = counts[base + 0];
        if (base + 1 < n) c.y = counts[base + 1];
        if (base + 2 < n) c.z = counts[base + 2];
    }
    const int s = c.x + c.y + c.z + c.w;
    ts[t] = s;
    __syncthreads();
    for (int off = 1; off < 256; off <<= 1) {
        int add = (t >= off) ? ts[t - off] : 0;
        __syncthreads();
        ts[t] += add;
        __syncthreads();
    }
    int excl = block_off + ts[t] - s;

    int4 w;
    w.x = excl;
    w.y = w.x + c.x;
    w.z = w.y + c.y;
    w.w = w.z + c.z;
    if (base + 4 <= n) {
        *reinterpret_cast<int4*>(starts + base) = w;
    } else if (base < n) {
        if (base + 0 < n) starts[base + 0] = w.x;
        if (base + 1 < n) starts[base + 1] = w.y;
        if (base + 2 < n) starts[base + 2] = w.z;
    }
    if (b == 0 && t == 0) starts[n] = sb[nB - 1];  // = nE
}

// Atomic-free scatter: position = starts[dst] + precomputed rank.
__global__ void k_scatter_nr(const int* __restrict__ src, const int* __restrict__ dst,
                             const int* __restrict__ rank, const int* __restrict__ starts,
                             int* __restrict__ esrc, int nE) {
    int e4 = (blockIdx.x * blockDim.x + threadIdx.x) * 4;
    if (e4 + 4 <= nE) {
        const int4 s = *reinterpret_cast<const int4*>(src + e4);
        const int4 d = *reinterpret_cast<const int4*>(dst + e4);
        const int4 r = *reinterpret_cast<const int4*>(rank + e4);
        esrc[starts[d.x] + r.x] = s.x;
        esrc[starts[d.y] + r.y] = s.y;
        esrc[starts[d.z] + r.z] = s.z;
        esrc[starts[d.w] + r.w] = s.w;
    } else {
        for (int e = e4; e < nE; ++e)
            esrc[starts[dst[e]] + rank[e]] = src[e];
    }
}

// ---------------- gather chunk core: 8-deep pipelined row accumulate ----------------
__device__ __forceinline__ void accum_chunk(const unsigned short* __restrict__ hs,
                                            int myedge, int cnt, int grp, int sub,
                                            float acc[8]) {
    auto row16 = [&](int s) -> u32x4 {
        return *reinterpret_cast<const u32x4*>(hs + (size_t)s * D + sub * 8);
    };
    for (int k = 0; k < cnt; k += 8) {
        u32x4 u[8];
#pragma unroll
        for (int q = 0; q < 8; ++q) {
            const int tq = min(k + q, cnt - 1);  // clamp: dupes hit L1
            const int s = __shfl(myedge, (grp << 4) | tq);
            u[q] = row16(s);
        }
        const int rem = cnt - k;
#pragma unroll
        for (int q = 0; q < 8; ++q) {
            if (q < rem) {
#pragma unroll
                for (int e = 0; e < 4; ++e) {
                    acc[2 * e] += bf_lo(u[q][e]);
                    acc[2 * e + 1] += bf_hi(u[q][e]);
                }
            }
        }
    }
}

// ---------------- MFMA GEMM (layer 1): hs_bf16[n,128] = dis .* (X @ W) ----------------
template <bool IN_BF16, bool RELU>
__global__ __launch_bounds__(256, 3) void k_gemm_mfma(const void* __restrict__ Xv,
                                                      const unsigned short* __restrict__ wp,
                                                      const float* __restrict__ dis,
                                                      unsigned short* __restrict__ outbf,
                                                      int n) {
    __shared__ __align__(16) unsigned short At[64 * 128];  // 16KB, swizzled
    const int tid = threadIdx.x;
    const int lane = tid & 63;
    const int wv = tid >> 6;
    const int col16 = lane & 15;
    const int kgrp = lane >> 4;
    const int st = blockIdx.x;

    // ---- issue A-tile loads first (longest latency) ----
    float4 pf[8];
    bf16x8 pb[4];
#pragma unroll
    for (int c = 0; c < 4; ++c) {
        const int idx = c * 2048 + tid * 8;
        const int row = idx >> 7;
        const int col = idx & 127;
        int grow = st * 64 + row;
        if (grow >= n) grow = n - 1;  // clamp reads; stores masked
        if constexpr (IN_BF16) {
            pb[c] = *reinterpret_cast<const bf16x8*>(
                    (const unsigned short*)Xv + (size_t)grow * D + col);
        } else {
            const float4* p = reinterpret_cast<const float4*>(
                    (const float*)Xv + (size_t)grow * D + col);
            pf[2 * c] = p[0];
            pf[2 * c + 1] = p[1];
        }
    }

    // ---- convert + ds_write (elem-swizzle col ^ ((row&7)<<3)) ----
#pragma unroll
    for (int c = 0; c < 4; ++c) {
        const int idx = c * 2048 + tid * 8;
        const int row = idx >> 7;
        const int col = idx & 127;
        bf16x8 d;
        if constexpr (IN_BF16) {
            d = pb[c];
            if (RELU) {
#pragma unroll
                for (int e = 0; e < 8; ++e)
                    d[e] = (short)((d[e] & (short)0x8000) ? 0 : d[e]);
            }
        } else {
            const float4 f0 = pf[2 * c], f1 = pf[2 * c + 1];
            float v[8] = {f0.x, f0.y, f0.z, f0.w, f1.x, f1.y, f1.z, f1.w};
#pragma unroll
            for (int e = 0; e < 8; ++e) {
                float f = v[e];
                if (RELU) f = fmaxf(f, 0.0f);
                d[e] = (short)f2bf(f);
            }
        }
        const int waddr = row * 128 + (col ^ ((row & 7) << 3));
        *reinterpret_cast<bf16x8*>(&At[waddr]) = d;
    }
    __syncthreads();

    // ---- ds_read X-fragments ----
    bf16x8 a[4];
#pragma unroll
    for (int kk = 0; kk < 4; ++kk) {
        const int raddr = (wv * 16 + col16) * 128 +
                          ((kk * 32 + kgrp * 8) ^ ((col16 & 7) << 3));
        a[kk] = *reinterpret_cast<const bf16x8*>(&At[raddr]);
    }

    const int node = st * 64 + wv * 16 + col16;
    const float dn = (node < n) ? dis[node] : 0.0f;
    unsigned short* op = outbf + (size_t)node * D + kgrp * 4;

    // ---- two ct-halves: load 16 W frags, 16 MFMA, store 4 cts ----
#pragma unroll
    for (int h = 0; h < 2; ++h) {
        bf16x8 bw[4][4];
#pragma unroll
        for (int c2 = 0; c2 < 4; ++c2)
#pragma unroll
            for (int kk = 0; kk < 4; ++kk)
                bw[c2][kk] = *reinterpret_cast<const bf16x8*>(
                        wp + (size_t)(((h * 4 + c2) * 4 + kk) * 64 + lane) * 8);

        f32x4 acc[4];
#pragma unroll
        for (int c2 = 0; c2 < 4; ++c2) acc[c2] = (f32x4){0.f, 0.f, 0.f, 0.f};
#pragma unroll
        for (int kk = 0; kk < 4; ++kk)
#pragma unroll
            for (int c2 = 0; c2 < 4; ++c2)  // SWAPPED operands: D = (X@W)^T
                acc[c2] = __builtin_amdgcn_mfma_f32_16x16x32_bf16(bw[c2][kk], a[kk], acc[c2], 0, 0, 0);

        if (node < n) {
#pragma unroll
            for (int c2 = 0; c2 < 4; ++c2) {
                uint2 w;
                w.x = (unsigned)f2bf(dn * acc[c2][0]) | ((unsigned)f2bf(dn * acc[c2][1]) << 16);
                w.y = (unsigned)f2bf(dn * acc[c2][2]) | ((unsigned)f2bf(dn * acc[c2][3]) << 16);
                *reinterpret_cast<uint2*>(op + (h * 4 + c2) * 16) = w;
            }
        }
    }
}

// ---------------- FUSED gather + GEMM (layer 1 agg + layer 2 matmul) ----------------
// R10: all 4 quads' metadata (starts, first esrc chunk, self-row, dis) issued
// up-front as independent loads; accumulation then runs per-quad with the 8-deep
// row pipeline. Converts 4 serial dependent chains/wave into 1 chain + wide body.
__global__ __launch_bounds__(256, 3) void k_gather_gemm(const unsigned short* __restrict__ hs,
                                                        const int* __restrict__ starts,
                                                        const int* __restrict__ esrc,
                                                        const float* __restrict__ dis,
                                                        const float* __restrict__ bias,
                                                        const unsigned short* __restrict__ wp,
                                                        unsigned short* __restrict__ outbf,
                                                        int n) {
    __shared__ __align__(16) unsigned short At[64 * 128];  // 16KB, swizzled
    const int tid = threadIdx.x;
    const int lane = tid & 63;
    const int wv = tid >> 6;
    const int col16 = lane & 15;
    const int kgrp = lane >> 4;
    const int grp = lane >> 4;   // node within 4-node quad
    const int sub = lane & 15;   // lane within node
    const int st = blockIdx.x;

    const float4 bv0 = reinterpret_cast<const float4*>(bias)[sub * 2 + 0];
    const float4 bv1 = reinterpret_cast<const float4*>(bias)[sub * 2 + 1];

    // ---- metadata for all 4 quads: independent loads, all in flight together ----
    int ic[4], beg[4], end[4], cnt0[4], my[4];
    float di[4];
    u32x4 selfrow[4];
#pragma unroll
    for (int p = 0; p < 4; ++p) {
        const int i = st * 64 + wv * 16 + p * 4 + grp;
        ic[p] = (i < n) ? i : (n - 1);
    }
#pragma unroll
    for (int p = 0; p < 4; ++p) {
        beg[p] = starts[ic[p]];
        end[p] = starts[ic[p] + 1];
        di[p] = dis[ic[p]];
        selfrow[p] = *reinterpret_cast<const u32x4*>(hs + (size_t)ic[p] * D + sub * 8);
    }
#pragma unroll
    for (int p = 0; p < 4; ++p) {
        cnt0[p] = min(end[p] - beg[p], 16);
        my[p] = (sub < cnt0[p]) ? esrc[beg[p] + sub] : 0;
    }

    // ---- accumulate per quad (loads for later quads already issued) ----
#pragma unroll
    for (int p = 0; p < 4; ++p) {
        float acc[8];
#pragma unroll
        for (int e = 0; e < 4; ++e) {
            acc[2 * e] = bf_lo(selfrow[p][e]);
            acc[2 * e + 1] = bf_hi(selfrow[p][e]);
        }
        if (cnt0[p] > 0) accum_chunk(hs, my[p], cnt0[p], grp, sub, acc);
        // rare chunks beyond 16 edges
        for (int j = beg[p] + 16; j < end[p]; j += 16) {
            const int cnt = min(end[p] - j, 16);
            const int me = (sub < cnt) ? esrc[j + sub] : 0;
            accum_chunk(hs, me, cnt, grp, sub, acc);
        }

        float o[8];
        o[0] = di[p] * acc[0] + bv0.x; o[1] = di[p] * acc[1] + bv0.y;
        o[2] = di[p] * acc[2] + bv0.z; o[3] = di[p] * acc[3] + bv0.w;
        o[4] = di[p] * acc[4] + bv1.x; o[5] = di[p] * acc[5] + bv1.y;
        o[6] = di[p] * acc[6] + bv1.z; o[7] = di[p] * acc[7] + bv1.w;

        u32x4 w;  // ReLU + bf16 pack
#pragma unroll
        for (int e = 0; e < 4; ++e)
            w[e] = (unsigned)f2bf(fmaxf(o[2 * e], 0.0f)) |
                   ((unsigned)f2bf(fmaxf(o[2 * e + 1], 0.0f)) << 16);
        const int lrow = wv * 16 + p * 4 + grp;
        const int waddr = lrow * 128 + ((sub * 8) ^ ((lrow & 7) << 3));
        *reinterpret_cast<u32x4*>(&At[waddr]) = w;
    }
    __syncthreads();

    // ---- GEMM phase ----
    bf16x8 a[4];
#pragma unroll
    for (int kk = 0; kk < 4; ++kk) {
        const int raddr = (wv * 16 + col16) * 128 +
                          ((kk * 32 + kgrp * 8) ^ ((col16 & 7) << 3));
        a[kk] = *reinterpret_cast<const bf16x8*>(&At[raddr]);
    }

    const int node = st * 64 + wv * 16 + col16;
    const float dn = (node < n) ? dis[node] : 0.0f;
    unsigned short* op = outbf + (size_t)node * D + kgrp * 4;

#pragma unroll
    for (int h = 0; h < 2; ++h) {
        bf16x8 bw[4][4];
#pragma unroll
        for (int c2 = 0; c2 < 4; ++c2)
#pragma unroll
            for (int kk = 0; kk < 4; ++kk)
                bw[c2][kk] = *reinterpret_cast<const bf16x8*>(
                        wp + (size_t)(((h * 4 + c2) * 4 + kk) * 64 + lane) * 8);

        f32x4 acc[4];
#pragma unroll
        for (int c2 = 0; c2 < 4; ++c2) acc[c2] = (f32x4){0.f, 0.f, 0.f, 0.f};
#pragma unroll
        for (int kk = 0; kk < 4; ++kk)
#pragma unroll
            for (int c2 = 0; c2 < 4; ++c2)
                acc[c2] = __builtin_amdgcn_mfma_f32_16x16x32_bf16(bw[c2][kk], a[kk], acc[c2], 0, 0, 0);

        if (node < n) {
#pragma unroll
            for (int c2 = 0; c2 < 4; ++c2) {
                uint2 w;
                w.x = (unsigned)f2bf(dn * acc[c2][0]) | ((unsigned)f2bf(dn * acc[c2][1]) << 16);
                w.y = (unsigned)f2bf(dn * acc[c2][2]) | ((unsigned)f2bf(dn * acc[c2][3]) << 16);
                *reinterpret_cast<uint2*>(op + (h * 4 + c2) * 16) = w;
            }
        }
    }
}

// ---------------- standalone gather-aggregate (layer 2 output, f32) ----------------
__global__ __launch_bounds__(256) void k_gather_agg(const unsigned short* __restrict__ hs,
                                                    const int* __restrict__ starts,
                                                    const int* __restrict__ esrc,
                                                    const float* __restrict__ dis,
                                                    const float* __restrict__ b,
                                                    float* __restrict__ outv, int n) {
    const int lane = threadIdx.x & 63;
    const int wv = threadIdx.x >> 6;
    const int grp = lane >> 4;
    const int sub = lane & 15;
    const int i = (blockIdx.x * 4 + wv) * 4 + grp;
    const bool active = (i < n);
    const int ic = active ? i : (n - 1);

    const float di = dis[ic];
    const int beg = starts[ic];
    const int end = starts[ic + 1];

    float acc[8];
    {   // self-loop row
        const u32x4 u = *reinterpret_cast<const u32x4*>(hs + (size_t)ic * D + sub * 8);
#pragma unroll
        for (int e = 0; e < 4; ++e) {
            acc[2 * e] = bf_lo(u[e]);
            acc[2 * e + 1] = bf_hi(u[e]);
        }
    }
    for (int j = beg; j < end; j += 16) {
        const int cnt = min(end - j, 16);
        const int me = (sub < cnt) ? esrc[j + sub] : 0;
        accum_chunk(hs, me, cnt, grp, sub, acc);
    }

    if (!active) return;

    const float4 bv0 = reinterpret_cast<const float4*>(b)[sub * 2 + 0];
    const float4 bv1 = reinterpret_cast<const float4*>(b)[sub * 2 + 1];
    float4* op = reinterpret_cast<float4*>(outv + (size_t)i * D + sub * 8);
    op[0] = make_float4(di * acc[0] + bv0.x, di * acc[1] + bv0.y,
                        di * acc[2] + bv0.z, di * acc[3] + bv0.w);
    op[1] = make_float4(di * acc[4] + bv1.x, di * acc[5] + bv1.y,
                        di * acc[6] + bv1.z, di * acc[7] + bv1.w);
}

extern "C" void kernel_launch(void* const* d_in, const int* in_sizes, int n_in,
                              void* d_out, int out_size, void* d_ws, size_t ws_size,
                              hipStream_t stream) {
    const float* x  = (const float*)d_in[0];
    const int*   ei = (const int*)d_in[1];   // [2, E]
    const float* W1 = (const float*)d_in[2];
    const float* b1 = (const float*)d_in[3];
    const float* W2 = (const float*)d_in[4];
    const float* b2 = (const float*)d_in[5];
    float* out = (float*)d_out;

    const int n  = in_sizes[0] / D;
    const int nE = in_sizes[1] / 2;
    const int* src = ei;
    const int* dst = ei + nE;

    char* ws = (char*)d_ws;
    float*          dis    = (float*)(ws);                  // n f32
    int*            counts = (int*)(ws + (1ull  << 19));    // n i32
    int*            starts = (int*)(ws + (2ull  << 19));    // n+1 i32
    int*            esrc   = (int*)(ws + (4ull  << 19));    // nE i32 (2..4.4M)
    int*            bsum   = (int*)(ws + (6ull  << 20));    // <=128 i32
    unsigned short* hs_bf  = (unsigned short*)(ws + (8ull  << 20));  // n*128 bf16
    int*            rank   = (int*)(ws + (34ull << 20));    // nE i32
    unsigned short* wp     = (unsigned short*)(ws + (37ull << 20));  // 64KB (both layers)
    unsigned short* hs2_bf = (unsigned short*)(ws + (40ull << 20));  // n*128 bf16

    unsigned short* wp1 = wp;
    unsigned short* wp2 = wp + 2048 * 8;

    const int B = 256;
    const int gn = (n + B - 1) / B;
    const int ge4 = (nE + B * 4 - 1) / (B * 4);
    const int nB = (n + 1023) / 1024;  // <=128 for n<=131072

    // W pre-pack (both layers) + counts zero, one launch
    k_pack_zero<<<16 + gn, B, 0, stream>>>(W1, W2, wp, counts, n);

    // CSR by dst (counts also yields degrees: deg = counts + 1 self-loop)
    k_hist_rank<<<ge4, B, 0, stream>>>(dst, counts, rank, nE);
    k_scan_part<<<nB, B, 0, stream>>>(counts, bsum, dis, n);
    k_scan_final<<<nB, B, 0, stream>>>(counts, bsum, starts, n, nB);
    k_scatter_nr<<<ge4, B, 0, stream>>>(src, dst, rank, starts, esrc, nE);

    const int nst = (n + 63) / 64;
    const int agg_grid = (n + 15) / 16;

    // ---- layer 1 GEMM: hs = dis .* (x @ W1) ----
    k_gemm_mfma<false, false><<<nst, B, 0, stream>>>(x, wp1, dis, hs_bf, n);
    // ---- FUSED: agg1(+b1,ReLU) -> @W2 -> hs2 = dis .* (relu(agg1) @ W2) ----
    k_gather_gemm<<<nst, B, 0, stream>>>(hs_bf, starts, esrc, dis, b1, wp2, hs2_bf, n);
    // ---- layer 2 aggregation -> f32 output ----
    k_gather_agg<<<agg_grid, B, 0, stream>>>(hs2_bf, starts, esrc, dis, b2, out, n);
}